// Round 1
// baseline (13748.445 us; speedup 1.0000x reference)
//
#include <hip/hip_runtime.h>
#include <math.h>

#define BB 32
#define TD 2048
#define TE 1024
#define DIM 256
#define INDIM 80
#define TT 8
#define NBLK (BB*TD/TT)   /* 8192 */

__device__ __forceinline__ float sigmoidf_(float x){ return 1.f/(1.f+__expf(-x)); }

// ---------------- input linear + shift-right ----------------
__global__ __launch_bounds__(256) void k_lin_in(const float* __restrict__ mel,
    const float* __restrict__ W, const float* __restrict__ bias, float* __restrict__ X)
{
  int blk = blockIdx.x;
  int b = blk >> 8;              // TD/TT = 256 blocks per batch
  int t0 = (blk & 255) * TT;
  __shared__ float ms[TT][INDIM];
  for (int i = threadIdx.x; i < TT*INDIM; i += 256) {
    int r = i / INDIM, c = i - r*INDIM;
    int mt = t0 + r - 1;                       // shifted: X[t] = lin(mel[t-1])
    ms[r][c] = (mt >= 0) ? mel[(b*TD + mt)*INDIM + c] : 0.f;
  }
  __syncthreads();
  int d = threadIdx.x;
  float acc[TT];
  float bb = bias[d];
  #pragma unroll
  for (int r=0;r<TT;r++) acc[r]=bb;
  for (int k=0;k<INDIM;k++){
    float w = W[d*INDIM + k];
    #pragma unroll
    for (int r=0;r<TT;r++) acc[r] = fmaf(w, ms[r][k], acc[r]);
  }
  #pragma unroll
  for (int r=0;r<TT;r++){
    int t = t0 + r;
    X[(b*TD + t)*DIM + d] = (t==0) ? 0.f : acc[r];
  }
}

// ---------------- causal conv1d (k=5, D->2D) + GLU + residual ----------------
__global__ __launch_bounds__(256) void k_conv_glu(const float* __restrict__ Xin,
    const float* __restrict__ w, const float* __restrict__ bias, float* __restrict__ Hout)
{
  int blk = blockIdx.x;
  int b = blk >> 8;
  int t0 = (blk & 255) * TT;
  __shared__ __align__(16) float xs[DIM][16];   // [channel][time], rows 64B aligned
  for (int i = threadIdx.x; i < (TT+4)*DIM; i += 256){
    int r = i >> 8, c = i & 255;
    int t = t0 - 4 + r;
    xs[c][r] = (t >= 0) ? Xin[(b*TD + t)*DIM + c] : 0.f;
  }
  __syncthreads();
  int d = threadIdx.x;
  float aa[TT], ag[TT];
  float ba = bias[d], bg = bias[d+DIM];
  #pragma unroll
  for (int r=0;r<TT;r++){ aa[r]=ba; ag[r]=bg; }
  const float* __restrict__ wa = w + (size_t)d*(DIM*5);
  const float* __restrict__ wg = w + (size_t)(d+DIM)*(DIM*5);
  #pragma unroll 4
  for (int ic=0; ic<DIM; ic++){
    const float4* row = (const float4*)&xs[ic][0];
    float4 x0 = row[0], x1 = row[1], x2 = row[2];
    float xv[12] = {x0.x,x0.y,x0.z,x0.w, x1.x,x1.y,x1.z,x1.w, x2.x,x2.y,x2.z,x2.w};
    #pragma unroll
    for (int k=0;k<5;k++){
      float fa = wa[ic*5+k];
      float fg = wg[ic*5+k];
      #pragma unroll
      for (int r=0;r<TT;r++){
        aa[r] = fmaf(fa, xv[r+k], aa[r]);
        ag[r] = fmaf(fg, xv[r+k], ag[r]);
      }
    }
  }
  const float is2 = 0.7071067811865476f;
  #pragma unroll
  for (int r=0;r<TT;r++){
    float hv = (aa[r]*sigmoidf_(ag[r]) + xs[d][r+4]) * is2;
    Hout[(b*TD + t0 + r)*DIM + d] = hv;
  }
}

// ---------------- enc + emb precompute ----------------
__global__ __launch_bounds__(256) void k_esum(const float4* __restrict__ enc,
    const float4* __restrict__ emb, float4* __restrict__ E)
{
  int i = blockIdx.x*256 + threadIdx.x;
  float4 a = enc[i], c = emb[i];
  E[i] = make_float4(a.x+c.x, a.y+c.y, a.z+c.z, a.w+c.w);
}

// ---------------- fused q-linear + attention (flash-block) + residual ----------------
__global__ __launch_bounds__(256) void k_attn(float* __restrict__ H,
    const float* __restrict__ Wq, const float* __restrict__ bq,
    const float* __restrict__ enc, const float* __restrict__ E)
{
  int blk = blockIdx.x;
  int b = blk >> 8;
  int t0 = (blk & 255)*TT;
  __shared__ __align__(16) float sc[TT][1032];   // scores; first 12KB aliased as hs
  __shared__ __align__(16) float qs[TT][260];
  __shared__ float red[TT][33];
  __shared__ float linv[TT];
  float (*hs)[12] = (float (*)[12])&sc[0][0];    // [256 k][12], only [0..7] used

  // stage h tile transposed (k-major) for broadcast-friendly q compute
  for (int i = threadIdx.x; i < TT*DIM; i += 256){
    int tt = i >> 8, k = i & 255;
    hs[k][tt] = H[(b*TD + t0 + tt)*DIM + k];
  }
  __syncthreads();

  // q[tt][d] = sum_k Wq[d][k] * h[tt][k] + bq[d]
  {
    int d = threadIdx.x;
    float qacc[TT];
    float bb = bq[d];
    #pragma unroll
    for (int tt=0;tt<TT;tt++) qacc[tt]=bb;
    const float4* w4 = (const float4*)(Wq + (size_t)d*DIM);
    for (int k4=0;k4<DIM/4;k4++){
      float4 wv = w4[k4];
      float wk[4] = {wv.x,wv.y,wv.z,wv.w};
      #pragma unroll
      for (int kk=0;kk<4;kk++){
        int k = k4*4+kk;
        float4 h0 = *(const float4*)&hs[k][0];
        float4 h1 = *(const float4*)&hs[k][4];
        qacc[0]=fmaf(wk[kk],h0.x,qacc[0]); qacc[1]=fmaf(wk[kk],h0.y,qacc[1]);
        qacc[2]=fmaf(wk[kk],h0.z,qacc[2]); qacc[3]=fmaf(wk[kk],h0.w,qacc[3]);
        qacc[4]=fmaf(wk[kk],h1.x,qacc[4]); qacc[5]=fmaf(wk[kk],h1.y,qacc[5]);
        qacc[6]=fmaf(wk[kk],h1.z,qacc[6]); qacc[7]=fmaf(wk[kk],h1.w,qacc[7]);
      }
    }
    __syncthreads();            // done reading hs (sc alias becomes writable)
    #pragma unroll
    for (int tt=0;tt<TT;tt++) qs[tt][d] = qacc[tt];
  }
  __syncthreads();

  // scores: thread (tt, ss) per 32-s chunk
  {
    int tt = threadIdx.x & 7;
    int ss = threadIdx.x >> 3;
    const float4* q4 = (const float4*)&qs[tt][0];
    for (int s0 = 0; s0 < TE; s0 += 32){
      const float4* e4 = (const float4*)(enc + ((size_t)b*TE + s0 + ss)*DIM);
      float acc = 0.f;
      for (int k=0;k<DIM/4;k++){
        float4 a = q4[k], c = e4[k];
        acc = fmaf(a.x,c.x,acc); acc = fmaf(a.y,c.y,acc);
        acc = fmaf(a.z,c.z,acc); acc = fmaf(a.w,c.w,acc);
      }
      sc[tt][s0+ss] = acc;
    }
  }
  __syncthreads();

  // softmax per t-row: 8 groups of 32 threads
  {
    int g = threadIdx.x >> 5, j = threadIdx.x & 31;
    float m = -3.0e38f;
    for (int s=j; s<TE; s+=32) m = fmaxf(m, sc[g][s]);
    red[g][j] = m;
    __syncthreads();
    for (int off=16; off>0; off>>=1){
      if (j < off) red[g][j] = fmaxf(red[g][j], red[g][j+off]);
      __syncthreads();
    }
    m = red[g][0];
    __syncthreads();
    float l = 0.f;
    for (int s=j; s<TE; s+=32){
      float p = __expf(sc[g][s] - m);
      sc[g][s] = p;
      l += p;
    }
    red[g][j] = l;
    __syncthreads();
    for (int off=16; off>0; off>>=1){
      if (j < off) red[g][j] += red[g][j+off];
      __syncthreads();
    }
    if (threadIdx.x < TT) linv[threadIdx.x] = 1.f / red[threadIdx.x][0];
    __syncthreads();
  }

  // PV: thread handles 2 d-columns x 4 t-rows; H += attn @ (enc+emb), normalized
  {
    int dp = (threadIdx.x & 127) * 2;
    int tg = (threadIdx.x >> 7) * 4;
    float a0[4], a1[4];
    #pragma unroll
    for (int q=0;q<4;q++){ a0[q]=0.f; a1[q]=0.f; }
    for (int s=0; s<TE; s+=4){
      const float* eb = E + ((size_t)b*TE + s)*DIM + dp;
      float2 e0 = *(const float2*)(eb);
      float2 e1 = *(const float2*)(eb + DIM);
      float2 e2 = *(const float2*)(eb + 2*DIM);
      float2 e3 = *(const float2*)(eb + 3*DIM);
      #pragma unroll
      for (int q=0;q<4;q++){
        float4 p = *(const float4*)&sc[tg+q][s];
        a0[q]=fmaf(p.x,e0.x,a0[q]); a1[q]=fmaf(p.x,e0.y,a1[q]);
        a0[q]=fmaf(p.y,e1.x,a0[q]); a1[q]=fmaf(p.y,e1.y,a1[q]);
        a0[q]=fmaf(p.z,e2.x,a0[q]); a1[q]=fmaf(p.z,e2.y,a1[q]);
        a0[q]=fmaf(p.w,e3.x,a0[q]); a1[q]=fmaf(p.w,e3.y,a1[q]);
      }
    }
    #pragma unroll
    for (int q=0;q<4;q++){
      float s2 = linv[tg+q];
      float* hp = &H[((size_t)b*TD + t0 + tg + q)*DIM + dp];
      hp[0] += a0[q]*s2;
      hp[1] += a1[q]*s2;
    }
  }
}

// ---------------- output projection 256 -> 80 ----------------
__global__ __launch_bounds__(256) void k_proj(const float* __restrict__ Hin,
    const float* __restrict__ W, const float* __restrict__ bias, float* __restrict__ out)
{
  int blk = blockIdx.x; int b = blk>>8; int t0 = (blk&255)*TT;
  __shared__ __align__(16) float hsr[TT][260];
  for (int i = threadIdx.x; i < TT*DIM; i += 256){
    int r = i>>8, c = i&255;
    hsr[r][c] = Hin[((size_t)b*TD+t0+r)*DIM + c];
  }
  __syncthreads();
  int g = threadIdx.x >> 5, j = threadIdx.x & 31;
  for (int i = j; i < INDIM; i += 32){
    float acc = bias[i];
    const float4* w4 = (const float4*)(W + (size_t)i*DIM);
    const float4* h4 = (const float4*)&hsr[g][0];
    for (int k=0;k<DIM/4;k++){
      float4 wv=w4[k], hv=h4[k];
      acc = fmaf(wv.x,hv.x,acc); acc=fmaf(wv.y,hv.y,acc);
      acc = fmaf(wv.z,hv.z,acc); acc=fmaf(wv.w,hv.w,acc);
    }
    out[((size_t)b*TD + t0 + g)*INDIM + i] = acc;
  }
}

extern "C" void kernel_launch(void* const* d_in, const int* in_sizes, int n_in,
                              void* d_out, int out_size, void* d_ws, size_t ws_size,
                              hipStream_t stream) {
  const float* enc   = (const float*)d_in[0];
  const float* emb   = (const float*)d_in[1];
  const float* mel   = (const float*)d_in[2];
  const float* W_lin = (const float*)d_in[3];
  const float* b_lin = (const float*)d_in[4];
  const float* w0    = (const float*)d_in[5];
  const float* b0    = (const float*)d_in[6];
  const float* w1    = (const float*)d_in[7];
  const float* b1    = (const float*)d_in[8];
  const float* Wq    = (const float*)d_in[9];
  const float* bq    = (const float*)d_in[10];
  const float* Wp    = (const float*)d_in[11];
  const float* bp    = (const float*)d_in[12];
  float* out = (float*)d_out;

  float* X = (float*)d_ws;                         // 16.8M floats
  float* H = X + (size_t)BB*TD*DIM;                // 16.8M floats
  float* E = X;                                    // aliases X: free after conv0, dead before conv1 writes

  k_lin_in <<<NBLK, 256, 0, stream>>>(mel, W_lin, b_lin, X);
  k_conv_glu<<<NBLK, 256, 0, stream>>>(X, w0, b0, H);
  k_esum   <<<(BB*TE*DIM/4)/256, 256, 0, stream>>>((const float4*)enc, (const float4*)emb, (float4*)E);
  k_attn   <<<NBLK, 256, 0, stream>>>(H, Wq, bq, enc, E);
  k_conv_glu<<<NBLK, 256, 0, stream>>>(H, w1, b1, X);
  k_proj   <<<NBLK, 256, 0, stream>>>(X, Wp, bp, out);
}

// Round 3
// 4929.215 us; speedup vs baseline: 2.7892x; 2.7892x over previous
//
#include <hip/hip_runtime.h>
#include <math.h>

#define BB 32
#define TD 2048
#define TE 1024
#define DIM 256
#define INDIM 80
#define TT 8
#define NBLK (BB*TD/TT)   /* 8192 */

typedef __attribute__((ext_vector_type(8))) short bf16x8;
typedef __attribute__((ext_vector_type(8))) unsigned short u16x8;
typedef __attribute__((ext_vector_type(4))) float f32x4;

__device__ __forceinline__ float sigmoidf_(float x){ return 1.f/(1.f+__expf(-x)); }
__device__ __forceinline__ unsigned short f2bf(float f){
  unsigned u = __float_as_uint(f);
  u += 0x7FFF + ((u>>16)&1);            // round-to-nearest-even
  return (unsigned short)(u>>16);
}
__device__ __forceinline__ float bf2f(unsigned short s){
  return __uint_as_float(((unsigned)s)<<16);
}

// ------- weight reorder + hi/lo split: w(512,256,5) f32 -> Whi/Wlo[o][tap*256+ic] -------
__global__ __launch_bounds__(256) void k_wprep(const float* __restrict__ w,
    unsigned short* __restrict__ Whi, unsigned short* __restrict__ Wlo)
{
  int i = blockIdx.x*256 + threadIdx.x;   // 512*1280 elements
  int o = i / 1280;
  int kk = i - o*1280;
  int tap = kk >> 8, ic = kk & 255;
  float f = w[(size_t)o*1280 + ic*5 + tap];
  unsigned short hi = f2bf(f);
  Whi[i] = hi;
  Wlo[i] = f2bf(f - bf2f(hi));
}

// ---------------- input linear + shift-right -> bf16 ----------------
__global__ __launch_bounds__(256) void k_lin_in(const float* __restrict__ mel,
    const float* __restrict__ W, const float* __restrict__ bias,
    unsigned short* __restrict__ X)
{
  int blk = blockIdx.x;
  int b = blk >> 8;
  int t0 = (blk & 255) * TT;
  __shared__ float ms[TT][INDIM];
  for (int i = threadIdx.x; i < TT*INDIM; i += 256) {
    int r = i / INDIM, c = i - r*INDIM;
    int mt = t0 + r - 1;                       // shifted: X[t] = lin(mel[t-1])
    ms[r][c] = (mt >= 0) ? mel[(b*TD + mt)*INDIM + c] : 0.f;
  }
  __syncthreads();
  int d = threadIdx.x;
  float acc[TT];
  float bb = bias[d];
  #pragma unroll
  for (int r=0;r<TT;r++) acc[r]=bb;
  for (int k=0;k<INDIM;k++){
    float w = W[d*INDIM + k];
    #pragma unroll
    for (int r=0;r<TT;r++) acc[r] = fmaf(w, ms[r][k], acc[r]);
  }
  #pragma unroll
  for (int r=0;r<TT;r++){
    int t = t0 + r;
    X[(b*TD + t)*DIM + d] = (t==0) ? (unsigned short)0 : f2bf(acc[r]);
  }
}

// ---------------- conv-GLU as bf16 MFMA GEMM, weights hi+lo split ----------------
// Y(t,o) = sum_{ic,tap} W[o][tap*256+ic] * X[t-4+tap][ic];  h=(a*sig(g)+x)/sqrt2
// TIN_F32/TOUT_F32 select fp32 vs bf16 global storage for in/out.
template<int TIN_F32, int TOUT_F32>
__global__ __launch_bounds__(256) void k_conv_mfma(const void* __restrict__ Xin_,
    const unsigned short* __restrict__ Whi, const unsigned short* __restrict__ Wlo,
    const float* __restrict__ bias, void* __restrict__ Hout_)
{
  __shared__ __align__(16) unsigned short as[68*264];   // rows t0-4..t0+63, pad 264
  int id = blockIdx.x;
  int dtile = id & 3, mtile = id >> 2;
  int b = mtile >> 5;
  int t0 = (mtile & 31) << 6;
  int d0 = dtile << 6;
  int tid = threadIdx.x;

  for (int i = tid; i < 68*32; i += 256){
    int row = i >> 5, cg = (i & 31) << 3;
    int t = t0 - 4 + row;
    u16x8 v = {};
    if (t >= 0){
      if (TIN_F32){
        const float4* p = (const float4*)((const float*)Xin_ + ((size_t)b*TD + t)*DIM + cg);
        float4 f0 = p[0], f1 = p[1];
        v[0]=f2bf(f0.x); v[1]=f2bf(f0.y); v[2]=f2bf(f0.z); v[3]=f2bf(f0.w);
        v[4]=f2bf(f1.x); v[5]=f2bf(f1.y); v[6]=f2bf(f1.z); v[7]=f2bf(f1.w);
      } else {
        v = *(const u16x8*)((const unsigned short*)Xin_ + ((size_t)b*TD + t)*DIM + cg);
      }
    }
    *(u16x8*)&as[row*264 + cg] = v;
  }
  __syncthreads();

  int lane = tid & 63, wave = tid >> 6;
  int l15 = lane & 15, l4 = lane >> 4;
  int m_base = (wave >> 1) << 5;
  int d_base = (wave & 1) << 5;

  int dA = d0 + d_base + l15;
  size_t r0 = (size_t)(dA      )*1280 + l4*8;
  size_t r1 = (size_t)(dA + 16 )*1280 + l4*8;
  size_t r2 = (size_t)(256 + dA)*1280 + l4*8;
  size_t r3 = (size_t)(272 + dA)*1280 + l4*8;

  f32x4 acc[2][4];
  #pragma unroll
  for (int mi=0;mi<2;mi++)
    #pragma unroll
    for (int j=0;j<4;j++) acc[mi][j] = (f32x4){0.f,0.f,0.f,0.f};

  for (int kc = 0; kc < 40; ++kc){
    int tap = kc >> 3;
    int ic0 = (kc & 7) << 5;
    int ar = (m_base + l15 + tap)*264 + ic0 + l4*8;
    bf16x8 av0 = *(bf16x8*)&as[ar];
    bf16x8 av1 = *(bf16x8*)&as[ar + 16*264];
    int ko = kc << 5;
    bf16x8 h0 = *(const bf16x8*)(Whi + r0 + ko);
    bf16x8 h1 = *(const bf16x8*)(Whi + r1 + ko);
    bf16x8 h2 = *(const bf16x8*)(Whi + r2 + ko);
    bf16x8 h3 = *(const bf16x8*)(Whi + r3 + ko);
    bf16x8 l0 = *(const bf16x8*)(Wlo + r0 + ko);
    bf16x8 l1 = *(const bf16x8*)(Wlo + r1 + ko);
    bf16x8 l2 = *(const bf16x8*)(Wlo + r2 + ko);
    bf16x8 l3 = *(const bf16x8*)(Wlo + r3 + ko);
    acc[0][0] = __builtin_amdgcn_mfma_f32_16x16x32_bf16(av0, l0, acc[0][0], 0,0,0);
    acc[0][1] = __builtin_amdgcn_mfma_f32_16x16x32_bf16(av0, l1, acc[0][1], 0,0,0);
    acc[0][2] = __builtin_amdgcn_mfma_f32_16x16x32_bf16(av0, l2, acc[0][2], 0,0,0);
    acc[0][3] = __builtin_amdgcn_mfma_f32_16x16x32_bf16(av0, l3, acc[0][3], 0,0,0);
    acc[1][0] = __builtin_amdgcn_mfma_f32_16x16x32_bf16(av1, l0, acc[1][0], 0,0,0);
    acc[1][1] = __builtin_amdgcn_mfma_f32_16x16x32_bf16(av1, l1, acc[1][1], 0,0,0);
    acc[1][2] = __builtin_amdgcn_mfma_f32_16x16x32_bf16(av1, l2, acc[1][2], 0,0,0);
    acc[1][3] = __builtin_amdgcn_mfma_f32_16x16x32_bf16(av1, l3, acc[1][3], 0,0,0);
    acc[0][0] = __builtin_amdgcn_mfma_f32_16x16x32_bf16(av0, h0, acc[0][0], 0,0,0);
    acc[0][1] = __builtin_amdgcn_mfma_f32_16x16x32_bf16(av0, h1, acc[0][1], 0,0,0);
    acc[0][2] = __builtin_amdgcn_mfma_f32_16x16x32_bf16(av0, h2, acc[0][2], 0,0,0);
    acc[0][3] = __builtin_amdgcn_mfma_f32_16x16x32_bf16(av0, h3, acc[0][3], 0,0,0);
    acc[1][0] = __builtin_amdgcn_mfma_f32_16x16x32_bf16(av1, h0, acc[1][0], 0,0,0);
    acc[1][1] = __builtin_amdgcn_mfma_f32_16x16x32_bf16(av1, h1, acc[1][1], 0,0,0);
    acc[1][2] = __builtin_amdgcn_mfma_f32_16x16x32_bf16(av1, h2, acc[1][2], 0,0,0);
    acc[1][3] = __builtin_amdgcn_mfma_f32_16x16x32_bf16(av1, h3, acc[1][3], 0,0,0);
  }

  const float is2 = 0.7071067811865476f;
  float ba0 = bias[dA],     bg0 = bias[256+dA];
  float ba1 = bias[dA+16],  bg1 = bias[256+dA+16];
  #pragma unroll
  for (int mi=0; mi<2; mi++){
    int mr = m_base + mi*16 + l4*4;
    #pragma unroll
    for (int r=0;r<4;r++){
      int m = mr + r;
      size_t orow = ((size_t)b*TD + t0 + m)*DIM;
      float xr0, xr1;
      if (TIN_F32){
        xr0 = ((const float*)Xin_)[orow + dA];
        xr1 = ((const float*)Xin_)[orow + dA + 16];
      } else {
        xr0 = bf2f(as[(m+4)*264 + dA]);
        xr1 = bf2f(as[(m+4)*264 + dA + 16]);
      }
      float a0v = acc[mi][0][r] + ba0;
      float a1v = acc[mi][1][r] + ba1;
      float g0v = acc[mi][2][r] + bg0;
      float g1v = acc[mi][3][r] + bg1;
      float o0 = (a0v*sigmoidf_(g0v) + xr0)*is2;
      float o1 = (a1v*sigmoidf_(g1v) + xr1)*is2;
      if (TOUT_F32){
        ((float*)Hout_)[orow + dA]      = o0;
        ((float*)Hout_)[orow + dA + 16] = o1;
      } else {
        ((unsigned short*)Hout_)[orow + dA]      = f2bf(o0);
        ((unsigned short*)Hout_)[orow + dA + 16] = f2bf(o1);
      }
    }
  }
}

// ---------------- enc + emb precompute ----------------
__global__ __launch_bounds__(256) void k_esum(const float4* __restrict__ enc,
    const float4* __restrict__ emb, float4* __restrict__ E)
{
  int i = blockIdx.x*256 + threadIdx.x;
  float4 a = enc[i], c = emb[i];
  E[i] = make_float4(a.x+c.x, a.y+c.y, a.z+c.z, a.w+c.w);
}

// ---------------- fused q-linear + attention + residual (fp32 H in-place) -------
__global__ __launch_bounds__(256) void k_attn(float* __restrict__ H,
    const float* __restrict__ Wq, const float* __restrict__ bq,
    const float* __restrict__ enc, const float* __restrict__ E)
{
  int blk = blockIdx.x;
  int b = blk >> 8;
  int t0 = (blk & 255)*TT;
  __shared__ __align__(16) float sc[TT][1032];   // scores; first 12KB aliased as hs
  __shared__ __align__(16) float qs[TT][260];
  __shared__ float red[TT][33];
  __shared__ float linv[TT];
  float (*hs)[12] = (float (*)[12])&sc[0][0];    // [256 k][12], only [0..7] used

  for (int i = threadIdx.x; i < TT*DIM; i += 256){
    int tt = i >> 8, k = i & 255;
    hs[k][tt] = H[(b*TD + t0 + tt)*DIM + k];
  }
  __syncthreads();

  {
    int d = threadIdx.x;
    float qacc[TT];
    float bb = bq[d];
    #pragma unroll
    for (int tt=0;tt<TT;tt++) qacc[tt]=bb;
    const float4* w4 = (const float4*)(Wq + (size_t)d*DIM);
    for (int k4=0;k4<DIM/4;k4++){
      float4 wv = w4[k4];
      float wk[4] = {wv.x,wv.y,wv.z,wv.w};
      #pragma unroll
      for (int kk=0;kk<4;kk++){
        int k = k4*4+kk;
        float4 h0 = *(const float4*)&hs[k][0];
        float4 h1 = *(const float4*)&hs[k][4];
        qacc[0]=fmaf(wk[kk],h0.x,qacc[0]); qacc[1]=fmaf(wk[kk],h0.y,qacc[1]);
        qacc[2]=fmaf(wk[kk],h0.z,qacc[2]); qacc[3]=fmaf(wk[kk],h0.w,qacc[3]);
        qacc[4]=fmaf(wk[kk],h1.x,qacc[4]); qacc[5]=fmaf(wk[kk],h1.y,qacc[5]);
        qacc[6]=fmaf(wk[kk],h1.z,qacc[6]); qacc[7]=fmaf(wk[kk],h1.w,qacc[7]);
      }
    }
    __syncthreads();
    #pragma unroll
    for (int tt=0;tt<TT;tt++) qs[tt][d] = qacc[tt];
  }
  __syncthreads();

  {
    int tt = threadIdx.x & 7;
    int ss = threadIdx.x >> 3;
    const float4* q4 = (const float4*)&qs[tt][0];
    for (int s0 = 0; s0 < TE; s0 += 32){
      const float4* e4 = (const float4*)(enc + ((size_t)b*TE + s0 + ss)*DIM);
      float acc = 0.f;
      for (int k=0;k<DIM/4;k++){
        float4 a = q4[k], c = e4[k];
        acc = fmaf(a.x,c.x,acc); acc = fmaf(a.y,c.y,acc);
        acc = fmaf(a.z,c.z,acc); acc = fmaf(a.w,c.w,acc);
      }
      sc[tt][s0+ss] = acc;
    }
  }
  __syncthreads();

  {
    int g = threadIdx.x >> 5, j = threadIdx.x & 31;
    float m = -3.0e38f;
    for (int s=j; s<TE; s+=32) m = fmaxf(m, sc[g][s]);
    red[g][j] = m;
    __syncthreads();
    for (int off=16; off>0; off>>=1){
      if (j < off) red[g][j] = fmaxf(red[g][j], red[g][j+off]);
      __syncthreads();
    }
    m = red[g][0];
    __syncthreads();
    float l = 0.f;
    for (int s=j; s<TE; s+=32){
      float p = __expf(sc[g][s] - m);
      sc[g][s] = p;
      l += p;
    }
    red[g][j] = l;
    __syncthreads();
    for (int off=16; off>0; off>>=1){
      if (j < off) red[g][j] += red[g][j+off];
      __syncthreads();
    }
    if (threadIdx.x < TT) linv[threadIdx.x] = 1.f / red[threadIdx.x][0];
    __syncthreads();
  }

  {
    int dp = (threadIdx.x & 127) * 2;
    int tg = (threadIdx.x >> 7) * 4;
    float a0[4], a1[4];
    #pragma unroll
    for (int q=0;q<4;q++){ a0[q]=0.f; a1[q]=0.f; }
    for (int s=0; s<TE; s+=4){
      const float* eb = E + ((size_t)b*TE + s)*DIM + dp;
      float2 e0 = *(const float2*)(eb);
      float2 e1 = *(const float2*)(eb + DIM);
      float2 e2 = *(const float2*)(eb + 2*DIM);
      float2 e3 = *(const float2*)(eb + 3*DIM);
      #pragma unroll
      for (int q=0;q<4;q++){
        float4 p = *(const float4*)&sc[tg+q][s];
        a0[q]=fmaf(p.x,e0.x,a0[q]); a1[q]=fmaf(p.x,e0.y,a1[q]);
        a0[q]=fmaf(p.y,e1.x,a0[q]); a1[q]=fmaf(p.y,e1.y,a1[q]);
        a0[q]=fmaf(p.z,e2.x,a0[q]); a1[q]=fmaf(p.z,e2.y,a1[q]);
        a0[q]=fmaf(p.w,e3.x,a0[q]); a1[q]=fmaf(p.w,e3.y,a1[q]);
      }
    }
    #pragma unroll
    for (int q=0;q<4;q++){
      float s2 = linv[tg+q];
      float* hp = &H[((size_t)b*TD + t0 + tg + q)*DIM + dp];
      hp[0] += a0[q]*s2;
      hp[1] += a1[q]*s2;
    }
  }
}

// ---------------- output projection 256 -> 80 (bf16 in, f32 out) ----------------
__global__ __launch_bounds__(256) void k_proj(const unsigned short* __restrict__ Hin,
    const float* __restrict__ W, const float* __restrict__ bias, float* __restrict__ out)
{
  int blk = blockIdx.x; int b = blk>>8; int t0 = (blk&255)*TT;
  __shared__ __align__(16) float hsr[TT][260];
  for (int i = threadIdx.x; i < TT*DIM; i += 256){
    int r = i>>8, c = i&255;
    hsr[r][c] = bf2f(Hin[((size_t)b*TD+t0+r)*DIM + c]);
  }
  __syncthreads();
  int g = threadIdx.x >> 5, j = threadIdx.x & 31;
  for (int i = j; i < INDIM; i += 32){
    float acc = bias[i];
    const float4* w4 = (const float4*)(W + (size_t)i*DIM);
    const float4* h4 = (const float4*)&hsr[g][0];
    for (int k=0;k<DIM/4;k++){
      float4 wv=w4[k], hv=h4[k];
      acc = fmaf(wv.x,hv.x,acc); acc=fmaf(wv.y,hv.y,acc);
      acc = fmaf(wv.z,hv.z,acc); acc=fmaf(wv.w,hv.w,acc);
    }
    out[((size_t)b*TD + t0 + g)*INDIM + i] = acc;
  }
}

extern "C" void kernel_launch(void* const* d_in, const int* in_sizes, int n_in,
                              void* d_out, int out_size, void* d_ws, size_t ws_size,
                              hipStream_t stream) {
  const float* enc   = (const float*)d_in[0];
  const float* emb   = (const float*)d_in[1];
  const float* mel   = (const float*)d_in[2];
  const float* W_lin = (const float*)d_in[3];
  const float* b_lin = (const float*)d_in[4];
  const float* w0    = (const float*)d_in[5];
  const float* b0    = (const float*)d_in[6];
  const float* w1    = (const float*)d_in[7];
  const float* b1    = (const float*)d_in[8];
  const float* Wq    = (const float*)d_in[9];
  const float* bq    = (const float*)d_in[10];
  const float* Wp    = (const float*)d_in[11];
  const float* bp    = (const float*)d_in[12];
  float* out = (float*)d_out;

  const size_t NTOK = (size_t)BB*TD*DIM;           // 16.78M elements
  // layout: [Xb bf16 33.5MB | H fp32 67MB | W0hi W0lo W1hi W1lo 5.24MB]
  // Xb region hosts X(bf16) -> E(fp32, same 33.5MB) -> Pb(bf16) sequentially.
  unsigned short* Xb  = (unsigned short*)d_ws;
  float*          H   = (float*)(Xb + NTOK);
  unsigned short* W0h = (unsigned short*)(H + NTOK);
  unsigned short* W0l = W0h + 512*1280;
  unsigned short* W1h = W0l + 512*1280;
  unsigned short* W1l = W1h + 512*1280;
  float*          E   = (float*)Xb;                // after conv0 consumes Xb
  unsigned short* Pb  = Xb;                        // after attn consumes E

  k_wprep   <<<2560, 256, 0, stream>>>(w0, W0h, W0l);
  k_wprep   <<<2560, 256, 0, stream>>>(w1, W1h, W1l);
  k_lin_in  <<<NBLK, 256, 0, stream>>>(mel, W_lin, b_lin, Xb);
  k_conv_mfma<0,1><<<4096, 256, 0, stream>>>(Xb, W0h, W0l, b0, H);
  k_esum    <<<(BB*TE*DIM/4)/256, 256, 0, stream>>>((const float4*)enc, (const float4*)emb, (float4*)E);
  k_attn    <<<NBLK, 256, 0, stream>>>(H, Wq, bq, enc, E);
  k_conv_mfma<1,0><<<4096, 256, 0, stream>>>(H, W1h, W1l, b1, Pb);
  k_proj    <<<NBLK, 256, 0, stream>>>(Pb, Wp, bp, out);
}

// Round 4
// 3097.967 us; speedup vs baseline: 4.4379x; 1.5911x over previous
//
#include <hip/hip_runtime.h>
#include <math.h>

#define BB 32
#define TD 2048
#define TE 1024
#define DIM 256
#define INDIM 80
#define TT 8
#define NBLK (BB*TD/TT)   /* 8192 */

typedef __attribute__((ext_vector_type(8))) short bf16x8;
typedef __attribute__((ext_vector_type(8))) unsigned short u16x8;
typedef __attribute__((ext_vector_type(4))) float f32x4;

__device__ __forceinline__ float sigmoidf_(float x){ return 1.f/(1.f+__expf(-x)); }
__device__ __forceinline__ unsigned short f2bf(float f){
  unsigned u = __float_as_uint(f);
  u += 0x7FFF + ((u>>16)&1);            // round-to-nearest-even
  return (unsigned short)(u>>16);
}
__device__ __forceinline__ float bf2f(unsigned short s){
  return __uint_as_float(((unsigned)s)<<16);
}

// ------- conv weight reorder + hi/lo split: w(512,256,5) -> Whi/Wlo[o][tap*256+ic] -------
__global__ __launch_bounds__(256) void k_wprep(const float* __restrict__ w,
    unsigned short* __restrict__ Whi, unsigned short* __restrict__ Wlo)
{
  int i = blockIdx.x*256 + threadIdx.x;   // 512*1280 elements
  int o = i / 1280;
  int kk = i - o*1280;
  int tap = kk >> 8, ic = kk & 255;
  float f = w[(size_t)o*1280 + ic*5 + tap];
  unsigned short hi = f2bf(f);
  Whi[i] = hi;
  Wlo[i] = f2bf(f - bf2f(hi));
}

// ------- Wq hi/lo split (row-major 256x256) -------
__global__ __launch_bounds__(256) void k_qwprep(const float* __restrict__ W,
    unsigned short* __restrict__ Wh, unsigned short* __restrict__ Wl)
{
  int i = blockIdx.x*256 + threadIdx.x;   // 65536
  float f = W[i];
  unsigned short h = f2bf(f);
  Wh[i] = h;
  Wl[i] = f2bf(f - bf2f(h));
}

// ------- enc prep: Eh/El = hi/lo(enc) [b][s][d];  EVt = bf16(enc+emb) transposed [b][d][s] ---
__global__ __launch_bounds__(256) void k_eprep(const float* __restrict__ enc,
    const float* __restrict__ emb, unsigned short* __restrict__ Eh,
    unsigned short* __restrict__ El, unsigned short* __restrict__ EVt)
{
  __shared__ float ls[64][65];
  int blk = blockIdx.x;                  // 32 b * 16 st * 4 dt = 2048
  int dt = blk & 3, st = (blk>>2) & 15, b = blk >> 6;
  int s0 = st*64, d0 = dt*64;
  int tid = threadIdx.x;
  for (int k=0;k<16;k++){
    int idx = k*256 + tid;
    int r = idx >> 6, c = idx & 63;      // r: s-local, c: d-local
    size_t gi = ((size_t)b*TE + s0 + r)*DIM + d0 + c;
    float e = enc[gi];
    float s = e + emb[gi];
    unsigned short h = f2bf(e);
    Eh[gi] = h;
    El[gi] = f2bf(e - bf2f(h));
    ls[r][c] = s;
  }
  __syncthreads();
  for (int k=0;k<16;k++){
    int idx = k*256 + tid;
    int r = idx >> 6, c = idx & 63;      // r: d-local, c: s-local
    EVt[((size_t)b*DIM + d0 + r)*TE + s0 + c] = f2bf(ls[c][r]);
  }
}

// ---------------- input linear + shift-right -> bf16 ----------------
__global__ __launch_bounds__(256) void k_lin_in(const float* __restrict__ mel,
    const float* __restrict__ W, const float* __restrict__ bias,
    unsigned short* __restrict__ X)
{
  int blk = blockIdx.x;
  int b = blk >> 8;
  int t0 = (blk & 255) * TT;
  __shared__ float ms[TT][INDIM];
  for (int i = threadIdx.x; i < TT*INDIM; i += 256) {
    int r = i / INDIM, c = i - r*INDIM;
    int mt = t0 + r - 1;
    ms[r][c] = (mt >= 0) ? mel[(b*TD + mt)*INDIM + c] : 0.f;
  }
  __syncthreads();
  int d = threadIdx.x;
  float acc[TT];
  float bb = bias[d];
  #pragma unroll
  for (int r=0;r<TT;r++) acc[r]=bb;
  for (int k=0;k<INDIM;k++){
    float w = W[d*INDIM + k];
    #pragma unroll
    for (int r=0;r<TT;r++) acc[r] = fmaf(w, ms[r][k], acc[r]);
  }
  #pragma unroll
  for (int r=0;r<TT;r++){
    int t = t0 + r;
    X[(b*TD + t)*DIM + d] = (t==0) ? (unsigned short)0 : f2bf(acc[r]);
  }
}

// ---------------- conv-GLU as bf16 MFMA GEMM, weights hi+lo split ----------------
template<int TIN_F32, int TOUT_F32>
__global__ __launch_bounds__(256) void k_conv_mfma(const void* __restrict__ Xin_,
    const unsigned short* __restrict__ Whi, const unsigned short* __restrict__ Wlo,
    const float* __restrict__ bias, void* __restrict__ Hout_)
{
  __shared__ __align__(16) unsigned short as[68*264];
  int id = blockIdx.x;
  int dtile = id & 3, mtile = id >> 2;
  int b = mtile >> 5;
  int t0 = (mtile & 31) << 6;
  int d0 = dtile << 6;
  int tid = threadIdx.x;

  for (int i = tid; i < 68*32; i += 256){
    int row = i >> 5, cg = (i & 31) << 3;
    int t = t0 - 4 + row;
    u16x8 v = {};
    if (t >= 0){
      if (TIN_F32){
        const float4* p = (const float4*)((const float*)Xin_ + ((size_t)b*TD + t)*DIM + cg);
        float4 f0 = p[0], f1 = p[1];
        v[0]=f2bf(f0.x); v[1]=f2bf(f0.y); v[2]=f2bf(f0.z); v[3]=f2bf(f0.w);
        v[4]=f2bf(f1.x); v[5]=f2bf(f1.y); v[6]=f2bf(f1.z); v[7]=f2bf(f1.w);
      } else {
        v = *(const u16x8*)((const unsigned short*)Xin_ + ((size_t)b*TD + t)*DIM + cg);
      }
    }
    *(u16x8*)&as[row*264 + cg] = v;
  }
  __syncthreads();

  int lane = tid & 63, wave = tid >> 6;
  int l15 = lane & 15, l4 = lane >> 4;
  int m_base = (wave >> 1) << 5;
  int d_base = (wave & 1) << 5;

  int dA = d0 + d_base + l15;
  size_t r0 = (size_t)(dA      )*1280 + l4*8;
  size_t r1 = (size_t)(dA + 16 )*1280 + l4*8;
  size_t r2 = (size_t)(256 + dA)*1280 + l4*8;
  size_t r3 = (size_t)(272 + dA)*1280 + l4*8;

  f32x4 acc[2][4];
  #pragma unroll
  for (int mi=0;mi<2;mi++)
    #pragma unroll
    for (int j=0;j<4;j++) acc[mi][j] = (f32x4){0.f,0.f,0.f,0.f};

  for (int kc = 0; kc < 40; ++kc){
    int tap = kc >> 3;
    int ic0 = (kc & 7) << 5;
    int ar = (m_base + l15 + tap)*264 + ic0 + l4*8;
    bf16x8 av0 = *(bf16x8*)&as[ar];
    bf16x8 av1 = *(bf16x8*)&as[ar + 16*264];
    int ko = kc << 5;
    bf16x8 h0 = *(const bf16x8*)(Whi + r0 + ko);
    bf16x8 h1 = *(const bf16x8*)(Whi + r1 + ko);
    bf16x8 h2 = *(const bf16x8*)(Whi + r2 + ko);
    bf16x8 h3 = *(const bf16x8*)(Whi + r3 + ko);
    bf16x8 l0 = *(const bf16x8*)(Wlo + r0 + ko);
    bf16x8 l1 = *(const bf16x8*)(Wlo + r1 + ko);
    bf16x8 l2 = *(const bf16x8*)(Wlo + r2 + ko);
    bf16x8 l3 = *(const bf16x8*)(Wlo + r3 + ko);
    acc[0][0] = __builtin_amdgcn_mfma_f32_16x16x32_bf16(av0, l0, acc[0][0], 0,0,0);
    acc[0][1] = __builtin_amdgcn_mfma_f32_16x16x32_bf16(av0, l1, acc[0][1], 0,0,0);
    acc[0][2] = __builtin_amdgcn_mfma_f32_16x16x32_bf16(av0, l2, acc[0][2], 0,0,0);
    acc[0][3] = __builtin_amdgcn_mfma_f32_16x16x32_bf16(av0, l3, acc[0][3], 0,0,0);
    acc[1][0] = __builtin_amdgcn_mfma_f32_16x16x32_bf16(av1, l0, acc[1][0], 0,0,0);
    acc[1][1] = __builtin_amdgcn_mfma_f32_16x16x32_bf16(av1, l1, acc[1][1], 0,0,0);
    acc[1][2] = __builtin_amdgcn_mfma_f32_16x16x32_bf16(av1, l2, acc[1][2], 0,0,0);
    acc[1][3] = __builtin_amdgcn_mfma_f32_16x16x32_bf16(av1, l3, acc[1][3], 0,0,0);
    acc[0][0] = __builtin_amdgcn_mfma_f32_16x16x32_bf16(av0, h0, acc[0][0], 0,0,0);
    acc[0][1] = __builtin_amdgcn_mfma_f32_16x16x32_bf16(av0, h1, acc[0][1], 0,0,0);
    acc[0][2] = __builtin_amdgcn_mfma_f32_16x16x32_bf16(av0, h2, acc[0][2], 0,0,0);
    acc[0][3] = __builtin_amdgcn_mfma_f32_16x16x32_bf16(av0, h3, acc[0][3], 0,0,0);
    acc[1][0] = __builtin_amdgcn_mfma_f32_16x16x32_bf16(av1, h0, acc[1][0], 0,0,0);
    acc[1][1] = __builtin_amdgcn_mfma_f32_16x16x32_bf16(av1, h1, acc[1][1], 0,0,0);
    acc[1][2] = __builtin_amdgcn_mfma_f32_16x16x32_bf16(av1, h2, acc[1][2], 0,0,0);
    acc[1][3] = __builtin_amdgcn_mfma_f32_16x16x32_bf16(av1, h3, acc[1][3], 0,0,0);
  }

  const float is2 = 0.7071067811865476f;
  float ba0 = bias[dA],     bg0 = bias[256+dA];
  float ba1 = bias[dA+16],  bg1 = bias[256+dA+16];
  #pragma unroll
  for (int mi=0; mi<2; mi++){
    int mr = m_base + mi*16 + l4*4;
    #pragma unroll
    for (int r=0;r<4;r++){
      int m = mr + r;
      size_t orow = ((size_t)b*TD + t0 + m)*DIM;
      float xr0, xr1;
      if (TIN_F32){
        xr0 = ((const float*)Xin_)[orow + dA];
        xr1 = ((const float*)Xin_)[orow + dA + 16];
      } else {
        xr0 = bf2f(as[(m+4)*264 + dA]);
        xr1 = bf2f(as[(m+4)*264 + dA + 16]);
      }
      float a0v = acc[mi][0][r] + ba0;
      float a1v = acc[mi][1][r] + ba1;
      float g0v = acc[mi][2][r] + bg0;
      float g1v = acc[mi][3][r] + bg1;
      float o0 = (a0v*sigmoidf_(g0v) + xr0)*is2;
      float o1 = (a1v*sigmoidf_(g1v) + xr1)*is2;
      if (TOUT_F32){
        ((float*)Hout_)[orow + dA]      = o0;
        ((float*)Hout_)[orow + dA + 16] = o1;
      } else {
        ((unsigned short*)Hout_)[orow + dA]      = f2bf(o0);
        ((unsigned short*)Hout_)[orow + dA + 16] = f2bf(o1);
      }
    }
  }
}

// ---------- fused q-linear + flash attention + residual, bf16 MFMA, H fp32 in place ------
// block = 64 t-rows, 4 independent waves x 16 rows. hi/lo split => near-fp32 logits.
__global__ __launch_bounds__(256) void k_attn(float* __restrict__ H,
    const unsigned short* __restrict__ Wqh, const unsigned short* __restrict__ Wql,
    const float* __restrict__ bq,
    const unsigned short* __restrict__ Eh, const unsigned short* __restrict__ El,
    const unsigned short* __restrict__ EVt)
{
  __shared__ __align__(16) unsigned short qh[64][264];   // H-hi, then Q-hi (per-wave rows)
  __shared__ __align__(16) unsigned short ql[64][264];   // H-lo, then Q-lo
  __shared__ __align__(16) unsigned short pbuf[4][16][72];

  int blk = blockIdx.x;                 // 32 b * 32 t-tiles
  int b = blk >> 5;
  int t0 = (blk & 31) << 6;
  int tid = threadIdx.x;
  int wave = tid >> 6, lane = tid & 63;
  int l15 = lane & 15, l4 = lane >> 4;
  int mb = wave << 4;

  // stage own 16 H rows as bf16 hi/lo
  for (int i = lane; i < 16*32; i += 64){
    int r = i >> 5, c8 = (i & 31) << 3;
    const float4* p = (const float4*)(H + ((size_t)b*TD + t0 + mb + r)*DIM + c8);
    float4 f0 = p[0], f1 = p[1];
    float ff[8] = {f0.x,f0.y,f0.z,f0.w,f1.x,f1.y,f1.z,f1.w};
    u16x8 vh, vl;
    #pragma unroll
    for (int j=0;j<8;j++){
      unsigned short h = f2bf(ff[j]);
      vh[j] = h; vl[j] = f2bf(ff[j] - bf2f(h));
    }
    *(u16x8*)&qh[mb+r][c8] = vh;
    *(u16x8*)&ql[mb+r][c8] = vl;
  }
  __syncthreads();

  // hoist H A-frags (own rows)
  bf16x8 ahh[8], ahl[8];
  #pragma unroll
  for (int kc=0;kc<8;kc++){
    int off = kc*32 + l4*8;
    ahh[kc] = *(bf16x8*)&qh[mb + l15][off];
    ahl[kc] = *(bf16x8*)&ql[mb + l15][off];
  }

  // q-GEMM: Q[16][256] = (Hh+Hl)(Wqh+Wql)^T, 3-term
  f32x4 qacc[16];
  #pragma unroll
  for (int ot=0;ot<16;ot++) qacc[ot] = (f32x4){0.f,0.f,0.f,0.f};
  for (int ot=0;ot<16;ot++){
    size_t wrow = (size_t)(ot*16 + l15)*256 + l4*8;
    f32x4 a = qacc[ot];
    #pragma unroll
    for (int kc=0;kc<8;kc++){
      bf16x8 bh = *(const bf16x8*)(Wqh + wrow + kc*32);
      bf16x8 bl = *(const bf16x8*)(Wql + wrow + kc*32);
      a = __builtin_amdgcn_mfma_f32_16x16x32_bf16(ahh[kc], bh, a, 0,0,0);
      a = __builtin_amdgcn_mfma_f32_16x16x32_bf16(ahl[kc], bh, a, 0,0,0);
      a = __builtin_amdgcn_mfma_f32_16x16x32_bf16(ahh[kc], bl, a, 0,0,0);
    }
    qacc[ot] = a;
  }
  __syncthreads();

  // write Q hi/lo (+bias) into qh/ql (own rows; C-layout -> row-major)
  #pragma unroll
  for (int ot=0;ot<16;ot++){
    int o = ot*16 + l15;
    float bqv = bq[o];
    #pragma unroll
    for (int r=0;r<4;r++){
      int m = mb + l4*4 + r;
      float v = qacc[ot][r] + bqv;
      unsigned short h = f2bf(v);
      qh[m][o] = h;
      ql[m][o] = f2bf(v - bf2f(h));
    }
  }
  __syncthreads();

  // hoist Q A-frags
  bf16x8 aqh[8], aql[8];
  #pragma unroll
  for (int kc=0;kc<8;kc++){
    int off = kc*32 + l4*8;
    aqh[kc] = *(bf16x8*)&qh[mb + l15][off];
    aql[kc] = *(bf16x8*)&ql[mb + l15][off];
  }

  // flash loop
  f32x4 oacc[16];
  #pragma unroll
  for (int dt=0;dt<16;dt++) oacc[dt] = (f32x4){0.f,0.f,0.f,0.f};
  float mrun[4], lrun[4];
  #pragma unroll
  for (int r=0;r<4;r++){ mrun[r] = -3.0e38f; lrun[r] = 0.f; }

  const unsigned short* Ehb = Eh + (size_t)b*TE*DIM;
  const unsigned short* Elb = El + (size_t)b*TE*DIM;
  const unsigned short* EVb = EVt + (size_t)b*DIM*TE;

  for (int s0 = 0; s0 < TE; s0 += 64){
    // scores: 4 tiles of 16 s, 3-term hi/lo
    f32x4 sacc[4];
    #pragma unroll
    for (int st=0;st<4;st++){
      size_t erow = (size_t)(s0 + st*16 + l15)*DIM + l4*8;
      f32x4 a = (f32x4){0.f,0.f,0.f,0.f};
      #pragma unroll
      for (int kc=0;kc<8;kc++){
        bf16x8 bh = *(const bf16x8*)(Ehb + erow + kc*32);
        bf16x8 bl = *(const bf16x8*)(Elb + erow + kc*32);
        a = __builtin_amdgcn_mfma_f32_16x16x32_bf16(aqh[kc], bh, a, 0,0,0);
        a = __builtin_amdgcn_mfma_f32_16x16x32_bf16(aql[kc], bh, a, 0,0,0);
        a = __builtin_amdgcn_mfma_f32_16x16x32_bf16(aqh[kc], bl, a, 0,0,0);
      }
      sacc[st] = a;
    }
    // online softmax; lane owns rows l4*4+r, cols st*16+l15
    float alpha[4];
    #pragma unroll
    for (int r=0;r<4;r++){
      float cm = fmaxf(fmaxf(sacc[0][r], sacc[1][r]), fmaxf(sacc[2][r], sacc[3][r]));
      cm = fmaxf(cm, __shfl_xor(cm, 1));
      cm = fmaxf(cm, __shfl_xor(cm, 2));
      cm = fmaxf(cm, __shfl_xor(cm, 4));
      cm = fmaxf(cm, __shfl_xor(cm, 8));
      float mnew = fmaxf(mrun[r], cm);
      alpha[r] = __expf(mrun[r] - mnew);
      mrun[r] = mnew;
      float ps = 0.f;
      #pragma unroll
      for (int st=0;st<4;st++){
        float p = __expf(sacc[st][r] - mnew);
        sacc[st][r] = p;
        ps += p;
      }
      ps += __shfl_xor(ps, 1);
      ps += __shfl_xor(ps, 2);
      ps += __shfl_xor(ps, 4);
      ps += __shfl_xor(ps, 8);
      lrun[r] = lrun[r]*alpha[r] + ps;
    }
    // rescale O, write P (bf16) to per-wave buffer
    #pragma unroll
    for (int dt=0;dt<16;dt++){
      #pragma unroll
      for (int r=0;r<4;r++) oacc[dt][r] *= alpha[r];
    }
    #pragma unroll
    for (int st=0;st<4;st++){
      #pragma unroll
      for (int r=0;r<4;r++)
        pbuf[wave][l4*4+r][st*16+l15] = f2bf(sacc[st][r]);
    }
    // PV: O[16][256] += P[16][64] * V[64][256]  (V = EVt rows, single bf16)
    #pragma unroll
    for (int kp=0;kp<2;kp++){
      bf16x8 ap = *(bf16x8*)&pbuf[wave][l15][kp*32 + l4*8];
      #pragma unroll
      for (int dt=0;dt<16;dt++){
        bf16x8 bv = *(const bf16x8*)(EVb + (size_t)(dt*16 + l15)*TE + s0 + kp*32 + l4*8);
        oacc[dt] = __builtin_amdgcn_mfma_f32_16x16x32_bf16(ap, bv, oacc[dt], 0,0,0);
      }
    }
  }

  // epilogue: H += O / l
  float linv[4];
  #pragma unroll
  for (int r=0;r<4;r++) linv[r] = 1.f / lrun[r];
  #pragma unroll
  for (int dt=0;dt<16;dt++){
    int d = dt*16 + l15;
    #pragma unroll
    for (int r=0;r<4;r++){
      int t = t0 + mb + l4*4 + r;
      float* hp = &H[((size_t)b*TD + t)*DIM + d];
      *hp += oacc[dt][r] * linv[r];
    }
  }
}

// ---------------- output projection 256 -> 80 (bf16 in, f32 out) ----------------
__global__ __launch_bounds__(256) void k_proj(const unsigned short* __restrict__ Hin,
    const float* __restrict__ W, const float* __restrict__ bias, float* __restrict__ out)
{
  int blk = blockIdx.x; int b = blk>>8; int t0 = (blk&255)*TT;
  __shared__ __align__(16) float hsr[TT][260];
  for (int i = threadIdx.x; i < TT*DIM; i += 256){
    int r = i>>8, c = i&255;
    hsr[r][c] = bf2f(Hin[((size_t)b*TD+t0+r)*DIM + c]);
  }
  __syncthreads();
  int g = threadIdx.x >> 5, j = threadIdx.x & 31;
  for (int i = j; i < INDIM; i += 32){
    float acc = bias[i];
    const float4* w4 = (const float4*)(W + (size_t)i*DIM);
    const float4* h4 = (const float4*)&hsr[g][0];
    for (int k=0;k<DIM/4;k++){
      float4 wv=w4[k], hv=h4[k];
      acc = fmaf(wv.x,hv.x,acc); acc=fmaf(wv.y,hv.y,acc);
      acc = fmaf(wv.z,hv.z,acc); acc=fmaf(wv.w,hv.w,acc);
    }
    out[((size_t)b*TD + t0 + g)*INDIM + i] = acc;
  }
}

extern "C" void kernel_launch(void* const* d_in, const int* in_sizes, int n_in,
                              void* d_out, int out_size, void* d_ws, size_t ws_size,
                              hipStream_t stream) {
  const float* enc   = (const float*)d_in[0];
  const float* emb   = (const float*)d_in[1];
  const float* mel   = (const float*)d_in[2];
  const float* W_lin = (const float*)d_in[3];
  const float* b_lin = (const float*)d_in[4];
  const float* w0    = (const float*)d_in[5];
  const float* b0    = (const float*)d_in[6];
  const float* w1    = (const float*)d_in[7];
  const float* b1    = (const float*)d_in[8];
  const float* Wq    = (const float*)d_in[9];
  const float* bq    = (const float*)d_in[10];
  const float* Wp    = (const float*)d_in[11];
  const float* bp    = (const float*)d_in[12];
  float* out = (float*)d_out;

  const size_t NTOK = (size_t)BB*TD*DIM;           // 16.78M
  const size_t NE   = (size_t)BB*TE*DIM;           // 8.39M
  // [A: 33.55MB  X -> (Eh|El) -> Pb] [H fp32 67MB] [conv W 5.24MB] [Wq 0.26MB] [EVt 16.78MB]
  unsigned short* Xb  = (unsigned short*)d_ws;
  float*          H   = (float*)(Xb + NTOK);
  unsigned short* W0h = (unsigned short*)(H + NTOK);
  unsigned short* W0l = W0h + 512*1280;
  unsigned short* W1h = W0l + 512*1280;
  unsigned short* W1l = W1h + 512*1280;
  unsigned short* Wqh = W1l + 512*1280;
  unsigned short* Wql = Wqh + 65536;
  unsigned short* EVt = Wql + 65536;
  unsigned short* Eh  = Xb;                        // after conv0 consumes Xb
  unsigned short* El  = Xb + NE;
  unsigned short* Pb  = Xb;                        // after attn consumes Eh/El

  k_wprep   <<<2560, 256, 0, stream>>>(w0, W0h, W0l);
  k_wprep   <<<2560, 256, 0, stream>>>(w1, W1h, W1l);
  k_qwprep  <<<256,  256, 0, stream>>>(Wq, Wqh, Wql);
  k_lin_in  <<<NBLK, 256, 0, stream>>>(mel, W_lin, b_lin, Xb);
  k_conv_mfma<0,1><<<4096, 256, 0, stream>>>(Xb, W0h, W0l, b0, H);
  k_eprep   <<<2048, 256, 0, stream>>>(enc, emb, Eh, El, EVt);
  k_attn    <<<1024, 256, 0, stream>>>(H, Wqh, Wql, bq, Eh, El, EVt);
  k_conv_mfma<1,0><<<4096, 256, 0, stream>>>(H, W1h, W1l, b1, Pb);
  k_proj    <<<NBLK, 256, 0, stream>>>(Pb, Wp, bp, out);
}

// Round 5
// 1496.968 us; speedup vs baseline: 9.1842x; 2.0695x over previous
//
#include <hip/hip_runtime.h>
#include <math.h>

#define BB 32
#define TD 2048
#define TE 1024
#define DIM 256
#define INDIM 80
#define TT 8
#define NBLK (BB*TD/TT)   /* 8192 */

typedef __attribute__((ext_vector_type(8))) _Float16 f16x8;
typedef __attribute__((ext_vector_type(4))) float f32x4;

__device__ __forceinline__ float sigmoidf_(float x){ return 1.f/(1.f+__expf(-x)); }

// ------- conv weight reorder: w(512,256,5) f32 -> Wf[o][tap*256+ic] fp16 -------
__global__ __launch_bounds__(256) void k_wprep(const float* __restrict__ w,
    _Float16* __restrict__ Wf)
{
  int i = blockIdx.x*256 + threadIdx.x;   // 512*1280
  int o = i / 1280;
  int kk = i - o*1280;
  int tap = kk >> 8, ic = kk & 255;
  Wf[i] = (_Float16)w[(size_t)o*1280 + ic*5 + tap];
}

// ------- Wq 2-term fp16 split (row-major 256x256) -------
__global__ __launch_bounds__(256) void k_qwprep(const float* __restrict__ W,
    _Float16* __restrict__ Wh, _Float16* __restrict__ Wl)
{
  int i = blockIdx.x*256 + threadIdx.x;   // 65536
  float f = W[i];
  _Float16 h = (_Float16)f;
  Wh[i] = h;
  Wl[i] = (_Float16)(f - (float)h);
}

// ------- enc prep: Eh = fp16(enc) [b][s][d];  EVt = fp16(enc+emb) transposed [b][d][s] ---
__global__ __launch_bounds__(256) void k_eprep(const float* __restrict__ enc,
    const float* __restrict__ emb, _Float16* __restrict__ Eh,
    _Float16* __restrict__ EVt)
{
  __shared__ float ls[64][65];
  int blk = blockIdx.x;                  // 32 b * 16 st * 4 dt = 2048
  int dt = blk & 3, st = (blk>>2) & 15, b = blk >> 6;
  int s0 = st*64, d0 = dt*64;
  int tid = threadIdx.x;
  for (int k=0;k<16;k++){
    int idx = k*256 + tid;
    int r = idx >> 6, c = idx & 63;      // r: s-local, c: d-local
    size_t gi = ((size_t)b*TE + s0 + r)*DIM + d0 + c;
    float e = enc[gi];
    ls[r][c] = e + emb[gi];
    Eh[gi] = (_Float16)e;
  }
  __syncthreads();
  for (int k=0;k<16;k++){
    int idx = k*256 + tid;
    int r = idx >> 6, c = idx & 63;      // r: d-local, c: s-local
    EVt[((size_t)b*DIM + d0 + r)*TE + s0 + c] = (_Float16)ls[c][r];
  }
}

// ---------------- input linear + shift-right -> fp16 ----------------
__global__ __launch_bounds__(256) void k_lin_in(const float* __restrict__ mel,
    const float* __restrict__ W, const float* __restrict__ bias,
    _Float16* __restrict__ X)
{
  int blk = blockIdx.x;
  int b = blk >> 8;
  int t0 = (blk & 255) * TT;
  __shared__ float ms[TT][INDIM];
  for (int i = threadIdx.x; i < TT*INDIM; i += 256) {
    int r = i / INDIM, c = i - r*INDIM;
    int mt = t0 + r - 1;
    ms[r][c] = (mt >= 0) ? mel[(b*TD + mt)*INDIM + c] : 0.f;
  }
  __syncthreads();
  int d = threadIdx.x;
  float acc[TT];
  float bb = bias[d];
  #pragma unroll
  for (int r=0;r<TT;r++) acc[r]=bb;
  for (int k=0;k<INDIM;k++){
    float w = W[d*INDIM + k];
    #pragma unroll
    for (int r=0;r<TT;r++) acc[r] = fmaf(w, ms[r][k], acc[r]);
  }
  #pragma unroll
  for (int r=0;r<TT;r++){
    int t = t0 + r;
    X[(b*TD + t)*DIM + d] = (t==0) ? (_Float16)0.f : (_Float16)acc[r];
  }
}

// ---------------- conv-GLU as fp16 MFMA GEMM ----------------
// wave owns 64 t-rows x 16 d-cols (a and g halves): per kc: 2 B loads (prefetched),
// 4 A ds_reads, 8 MFMAs -> 4:1 MFMA:global-load ratio.
template<int TIN_F32, int TOUT_F32>
__global__ __launch_bounds__(256) void k_conv_mfma(const void* __restrict__ Xin_,
    const _Float16* __restrict__ Wf, const float* __restrict__ bias,
    void* __restrict__ Hout_)
{
  __shared__ __align__(16) _Float16 as[68*264];   // 35.9 KB
  int id = blockIdx.x;
  int dtile = id & 3, mtile = id >> 2;
  int b = mtile >> 5;
  int t0 = (mtile & 31) << 6;
  int d0 = dtile << 6;
  int tid = threadIdx.x;

  for (int i = tid; i < 68*32; i += 256){
    int row = i >> 5, cg = (i & 31) << 3;
    int t = t0 - 4 + row;
    f16x8 v = {};
    if (t >= 0){
      if (TIN_F32){
        const float4* p = (const float4*)((const float*)Xin_ + ((size_t)b*TD + t)*DIM + cg);
        float4 f0 = p[0], f1 = p[1];
        v[0]=(_Float16)f0.x; v[1]=(_Float16)f0.y; v[2]=(_Float16)f0.z; v[3]=(_Float16)f0.w;
        v[4]=(_Float16)f1.x; v[5]=(_Float16)f1.y; v[6]=(_Float16)f1.z; v[7]=(_Float16)f1.w;
      } else {
        v = *(const f16x8*)((const _Float16*)Xin_ + ((size_t)b*TD + t)*DIM + cg);
      }
    }
    *(f16x8*)&as[row*264 + cg] = v;
  }
  __syncthreads();

  int lane = tid & 63, wave = tid >> 6;
  int l15 = lane & 15, l4 = lane >> 4;
  int dA = d0 + (wave << 4) + l15;

  const _Float16* pA = Wf + (size_t)dA*1280 + l4*8;
  const _Float16* pG = Wf + (size_t)(256 + dA)*1280 + l4*8;

  f32x4 aca[4], acg[4];
  #pragma unroll
  for (int mt=0;mt<4;mt++){ aca[mt]=(f32x4){0.f,0.f,0.f,0.f}; acg[mt]=(f32x4){0.f,0.f,0.f,0.f}; }

  f16x8 bA = *(const f16x8*)pA;
  f16x8 bG = *(const f16x8*)pG;
  #pragma unroll
  for (int kc = 0; kc < 40; ++kc){
    f16x8 nA = bA, nG = bG;
    if (kc < 39){
      nA = *(const f16x8*)(pA + (kc+1)*32);
      nG = *(const f16x8*)(pG + (kc+1)*32);
    }
    int tap = kc >> 3;
    int ic0 = (kc & 7) << 5;
    int abase = (l15 + tap)*264 + ic0 + l4*8;
    #pragma unroll
    for (int mt=0;mt<4;mt++){
      f16x8 av = *(f16x8*)&as[abase + mt*16*264];
      aca[mt] = __builtin_amdgcn_mfma_f32_16x16x32_f16(av, bA, aca[mt], 0,0,0);
      acg[mt] = __builtin_amdgcn_mfma_f32_16x16x32_f16(av, bG, acg[mt], 0,0,0);
    }
    bA = nA; bG = nG;
  }

  const float is2 = 0.7071067811865476f;
  float ba = bias[dA], bg = bias[256 + dA];
  #pragma unroll
  for (int mt=0; mt<4; mt++){
    #pragma unroll
    for (int r=0;r<4;r++){
      int m = mt*16 + l4*4 + r;
      size_t orow = ((size_t)b*TD + t0 + m)*DIM;
      float xr = TIN_F32 ? ((const float*)Xin_)[orow + dA]
                         : (float)as[(m+4)*264 + dA];
      float a = aca[mt][r] + ba;
      float g = acg[mt][r] + bg;
      float o = (a*sigmoidf_(g) + xr)*is2;
      if (TOUT_F32) ((float*)Hout_)[orow + dA] = o;
      else          ((_Float16*)Hout_)[orow + dA] = (_Float16)o;
    }
  }
}

// ---------- fused q-linear + flash attention + residual; fp16 MFMA, LDS-staged K/V ------
__global__ __launch_bounds__(256) void k_attn(float* __restrict__ H,
    const _Float16* __restrict__ Wqh, const _Float16* __restrict__ Wql,
    const float* __restrict__ bq,
    const _Float16* __restrict__ Eh, const _Float16* __restrict__ EVt)
{
  __shared__ __align__(16) _Float16 ech[64*264];        // E chunk / Q transit (33.8 KB)
  __shared__ __align__(16) _Float16 evch[256*72];       // V chunk (36.9 KB)
  __shared__ __align__(16) _Float16 pbuf[4][16][72];    // 9.2 KB

  int i = blockIdx.x;                   // XCD swizzle: same-batch blocks share an XCD
  int b = (i & 7) | ((i >> 8) << 3);    // i>>8 in [0,4)
  int t0 = ((i >> 3) & 31) << 6;
  int tid = threadIdx.x;
  int wave = tid >> 6, lane = tid & 63;
  int l15 = lane & 15, l4 = lane >> 4;
  int mb = wave << 4;

  // --- H A-frags direct from global (single fp16) ---
  f16x8 ah[8];
  {
    const float* hrow = H + ((size_t)b*TD + t0 + mb + l15)*DIM;
    #pragma unroll
    for (int kc=0;kc<8;kc++){
      const float4* p = (const float4*)(hrow + kc*32 + l4*8);
      float4 f0 = p[0], f1 = p[1];
      f16x8 v;
      v[0]=(_Float16)f0.x; v[1]=(_Float16)f0.y; v[2]=(_Float16)f0.z; v[3]=(_Float16)f0.w;
      v[4]=(_Float16)f1.x; v[5]=(_Float16)f1.y; v[6]=(_Float16)f1.z; v[7]=(_Float16)f1.w;
      ah[kc] = v;
    }
  }

  // --- q-GEMM: Q = H (fp16) @ (Wqh+Wql)^T, fp32 acc ---
  f32x4 qacc[16];
  for (int ot=0;ot<16;ot++){
    size_t wrow = (size_t)(ot*16 + l15)*256 + l4*8;
    f32x4 a = (f32x4){0.f,0.f,0.f,0.f};
    #pragma unroll
    for (int kc=0;kc<8;kc++){
      f16x8 bh = *(const f16x8*)(Wqh + wrow + kc*32);
      f16x8 bl = *(const f16x8*)(Wql + wrow + kc*32);
      a = __builtin_amdgcn_mfma_f32_16x16x32_f16(ah[kc], bh, a, 0,0,0);
      a = __builtin_amdgcn_mfma_f32_16x16x32_f16(ah[kc], bl, a, 0,0,0);
    }
    qacc[ot] = a;
  }
  // add bias
  #pragma unroll
  for (int ot=0;ot<16;ot++){
    float bqv = bq[ot*16 + l15];
    #pragma unroll
    for (int r=0;r<4;r++) qacc[ot][r] += bqv;
  }

  // --- Q transit through ech (wave-private rows): hi pass then lo pass ---
  #pragma unroll
  for (int ot=0;ot<16;ot++){
    int o = ot*16 + l15;
    #pragma unroll
    for (int r=0;r<4;r++)
      ech[(mb + l4*4 + r)*264 + o] = (_Float16)qacc[ot][r];
  }
  f16x8 aqh[8];
  #pragma unroll
  for (int kc=0;kc<8;kc++) aqh[kc] = *(f16x8*)&ech[(mb + l15)*264 + kc*32 + l4*8];
  #pragma unroll
  for (int ot=0;ot<16;ot++){
    int o = ot*16 + l15;
    #pragma unroll
    for (int r=0;r<4;r++){
      float v = qacc[ot][r];
      _Float16 h = (_Float16)v;
      ech[(mb + l4*4 + r)*264 + o] = (_Float16)(v - (float)h);
    }
  }
  f16x8 aql[8];
  #pragma unroll
  for (int kc=0;kc<8;kc++) aql[kc] = *(f16x8*)&ech[(mb + l15)*264 + kc*32 + l4*8];

  // --- flash loop ---
  f32x4 oacc[16];
  #pragma unroll
  for (int dt=0;dt<16;dt++) oacc[dt] = (f32x4){0.f,0.f,0.f,0.f};
  float mrun[4], lrun[4];
  #pragma unroll
  for (int r=0;r<4;r++){ mrun[r] = -3.0e38f; lrun[r] = 0.f; }

  const _Float16* Ehb = Eh + (size_t)b*TE*DIM;
  const _Float16* EVb = EVt + (size_t)b*DIM*TE;

  for (int s0 = 0; s0 < TE; s0 += 64){
    __syncthreads();                       // ech/evch free (also covers Q-transit)
    #pragma unroll
    for (int it=0; it<8; it++){            // stage Eh chunk [64][256] -> ech padded
      int slot = it*256 + tid;
      int row = slot >> 5, cg = (slot & 31) << 3;
      *(f16x8*)&ech[row*264 + cg] = *(const f16x8*)(Ehb + (size_t)(s0+row)*DIM + cg);
    }
    #pragma unroll
    for (int it=0; it<8; it++){            // stage EVt chunk [256][64] -> evch padded
      int slot = it*256 + tid;
      int row = slot >> 3, cg = (slot & 7) << 3;
      *(f16x8*)&evch[row*72 + cg] = *(const f16x8*)(EVb + (size_t)row*TE + s0 + cg);
    }
    __syncthreads();

    // scores: 4 tiles of 16 s; Q 2-term vs single-fp16 E
    f32x4 sacc[4];
    #pragma unroll
    for (int st=0;st<4;st++){
      int er = (st*16 + l15)*264 + l4*8;
      f32x4 a = (f32x4){0.f,0.f,0.f,0.f};
      #pragma unroll
      for (int kc=0;kc<8;kc++){
        f16x8 bh = *(f16x8*)&ech[er + kc*32];
        a = __builtin_amdgcn_mfma_f32_16x16x32_f16(aqh[kc], bh, a, 0,0,0);
        a = __builtin_amdgcn_mfma_f32_16x16x32_f16(aql[kc], bh, a, 0,0,0);
      }
      sacc[st] = a;
    }
    // online softmax; lane owns rows l4*4+r, cols st*16+l15
    float alpha[4];
    #pragma unroll
    for (int r=0;r<4;r++){
      float cm = fmaxf(fmaxf(sacc[0][r], sacc[1][r]), fmaxf(sacc[2][r], sacc[3][r]));
      cm = fmaxf(cm, __shfl_xor(cm, 1));
      cm = fmaxf(cm, __shfl_xor(cm, 2));
      cm = fmaxf(cm, __shfl_xor(cm, 4));
      cm = fmaxf(cm, __shfl_xor(cm, 8));
      float mnew = fmaxf(mrun[r], cm);
      alpha[r] = __expf(mrun[r] - mnew);
      mrun[r] = mnew;
      float ps = 0.f;
      #pragma unroll
      for (int st=0;st<4;st++){
        float p = __expf(sacc[st][r] - mnew);
        sacc[st][r] = p;
        ps += p;
      }
      ps += __shfl_xor(ps, 1);
      ps += __shfl_xor(ps, 2);
      ps += __shfl_xor(ps, 4);
      ps += __shfl_xor(ps, 8);
      lrun[r] = lrun[r]*alpha[r] + ps;
    }
    // rescale O, transpose P via wave-private pbuf
    #pragma unroll
    for (int dt=0;dt<16;dt++){
      #pragma unroll
      for (int r=0;r<4;r++) oacc[dt][r] *= alpha[r];
    }
    #pragma unroll
    for (int st=0;st<4;st++){
      #pragma unroll
      for (int r=0;r<4;r++)
        pbuf[wave][l4*4+r][st*16+l15] = (_Float16)sacc[st][r];
    }
    // PV: O[16][256] += P[16][64] * V[64][256] (B from evch)
    #pragma unroll
    for (int kp=0;kp<2;kp++){
      f16x8 ap = *(f16x8*)&pbuf[wave][l15][kp*32 + l4*8];
      #pragma unroll
      for (int dt=0;dt<16;dt++){
        f16x8 bv = *(f16x8*)&evch[(dt*16 + l15)*72 + kp*32 + l4*8];
        oacc[dt] = __builtin_amdgcn_mfma_f32_16x16x32_f16(ap, bv, oacc[dt], 0,0,0);
      }
    }
  }

  // epilogue: H += O / l
  float linv[4];
  #pragma unroll
  for (int r=0;r<4;r++) linv[r] = 1.f / lrun[r];
  #pragma unroll
  for (int dt=0;dt<16;dt++){
    int d = dt*16 + l15;
    #pragma unroll
    for (int r=0;r<4;r++){
      int t = t0 + mb + l4*4 + r;
      float* hp = &H[((size_t)b*TD + t)*DIM + d];
      *hp += oacc[dt][r] * linv[r];
    }
  }
}

// ---------------- output projection 256 -> 80 (fp16 in, f32 out) ----------------
__global__ __launch_bounds__(256) void k_proj(const _Float16* __restrict__ Hin,
    const float* __restrict__ W, const float* __restrict__ bias, float* __restrict__ out)
{
  int blk = blockIdx.x; int b = blk>>8; int t0 = (blk&255)*TT;
  __shared__ __align__(16) float hsr[TT][260];
  for (int i = threadIdx.x; i < TT*DIM; i += 256){
    int r = i>>8, c = i&255;
    hsr[r][c] = (float)Hin[((size_t)b*TD+t0+r)*DIM + c];
  }
  __syncthreads();
  int g = threadIdx.x >> 5, j = threadIdx.x & 31;
  for (int i = j; i < INDIM; i += 32){
    float acc = bias[i];
    const float4* w4 = (const float4*)(W + (size_t)i*DIM);
    const float4* h4 = (const float4*)&hsr[g][0];
    for (int k=0;k<DIM/4;k++){
      float4 wv=w4[k], hv=h4[k];
      acc = fmaf(wv.x,hv.x,acc); acc=fmaf(wv.y,hv.y,acc);
      acc = fmaf(wv.z,hv.z,acc); acc=fmaf(wv.w,hv.w,acc);
    }
    out[((size_t)b*TD + t0 + g)*INDIM + i] = acc;
  }
}

extern "C" void kernel_launch(void* const* d_in, const int* in_sizes, int n_in,
                              void* d_out, int out_size, void* d_ws, size_t ws_size,
                              hipStream_t stream) {
  const float* enc   = (const float*)d_in[0];
  const float* emb   = (const float*)d_in[1];
  const float* mel   = (const float*)d_in[2];
  const float* W_lin = (const float*)d_in[3];
  const float* b_lin = (const float*)d_in[4];
  const float* w0    = (const float*)d_in[5];
  const float* b0    = (const float*)d_in[6];
  const float* w1    = (const float*)d_in[7];
  const float* b1    = (const float*)d_in[8];
  const float* Wq    = (const float*)d_in[9];
  const float* bq    = (const float*)d_in[10];
  const float* Wp    = (const float*)d_in[11];
  const float* bp    = (const float*)d_in[12];
  float* out = (float*)d_out;

  const size_t NTOK = (size_t)BB*TD*DIM;           // 16.78M
  const size_t NE   = (size_t)BB*TE*DIM;           // 8.39M
  // [Xb fp16 33.55MB: X -> (Eh|EVt) -> Pb] [H fp32 67.1MB] [Wf0 Wf1 2.62MB] [Wqh Wql 0.26MB]
  _Float16* Xb  = (_Float16*)d_ws;
  float*    H   = (float*)(Xb + NTOK);
  _Float16* Wf0 = (_Float16*)(H + NTOK);
  _Float16* Wf1 = Wf0 + (size_t)512*1280;
  _Float16* Wqh = Wf1 + (size_t)512*1280;
  _Float16* Wql = Wqh + 65536;
  _Float16* Eh  = Xb;                              // after conv0 consumes Xb
  _Float16* EVt = Xb + NE;                         // NE+NE == NTOK exactly
  _Float16* Pb  = Xb;                              // after attn consumes Eh/EVt

  k_wprep   <<<2560, 256, 0, stream>>>(w0, Wf0);
  k_wprep   <<<2560, 256, 0, stream>>>(w1, Wf1);
  k_qwprep  <<<256,  256, 0, stream>>>(Wq, Wqh, Wql);
  k_lin_in  <<<NBLK, 256, 0, stream>>>(mel, W_lin, b_lin, Xb);
  k_conv_mfma<0,1><<<4096, 256, 0, stream>>>(Xb, Wf0, b0, H);
  k_eprep   <<<2048, 256, 0, stream>>>(enc, emb, Eh, EVt);
  k_attn    <<<1024, 256, 0, stream>>>(H, Wqh, Wql, bq, Eh, EVt);
  k_conv_mfma<1,0><<<4096, 256, 0, stream>>>(H, Wf1, b1, Pb);
  k_proj    <<<NBLK, 256, 0, stream>>>(Pb, Wp, bp, out);
}

// Round 6
// 896.294 us; speedup vs baseline: 15.3392x; 1.6702x over previous
//
#include <hip/hip_runtime.h>
#include <math.h>

#define BB 32
#define TD 2048
#define TE 1024
#define DIM 256
#define INDIM 80

typedef __attribute__((ext_vector_type(8))) _Float16 f16x8;
typedef __attribute__((ext_vector_type(4))) float f32x4;

__device__ __forceinline__ float sigmoidf_(float x){ return 1.f/(1.f+__expf(-x)); }

// ------- conv weight reorder: w(512,256,5) f32 -> Wf[o][tap*256+ic] fp16 -------
__global__ __launch_bounds__(256) void k_wprep(const float* __restrict__ w,
    _Float16* __restrict__ Wf)
{
  int i = blockIdx.x*256 + threadIdx.x;   // 512*1280
  int o = i / 1280;
  int kk = i - o*1280;
  int tap = kk >> 8, ic = kk & 255;
  Wf[i] = (_Float16)w[(size_t)o*1280 + ic*5 + tap];
}

// ------- Wq 2-term fp16 split (row-major 256x256) -------
__global__ __launch_bounds__(256) void k_qwprep(const float* __restrict__ W,
    _Float16* __restrict__ Wh, _Float16* __restrict__ Wl)
{
  int i = blockIdx.x*256 + threadIdx.x;   // 65536
  float f = W[i];
  _Float16 h = (_Float16)f;
  Wh[i] = h;
  Wl[i] = (_Float16)(f - (float)h);
}

// ------- W_lin 2-term fp16 split, padded: (256,80) -> [256][96] -------
__global__ __launch_bounds__(256) void k_lwprep(const float* __restrict__ W,
    _Float16* __restrict__ Wh, _Float16* __restrict__ Wl)
{
  int i = blockIdx.x*256 + threadIdx.x;   // 256*96
  int d = i / 96, k = i - d*96;
  float f = (k < INDIM) ? W[d*INDIM + k] : 0.f;
  _Float16 h = (_Float16)f;
  Wh[i] = h;
  Wl[i] = (_Float16)(f - (float)h);
}

// ------- W_proj 2-term fp16 split (row-major 80x256) -------
__global__ __launch_bounds__(256) void k_pwprep(const float* __restrict__ W,
    _Float16* __restrict__ Wh, _Float16* __restrict__ Wl)
{
  int i = blockIdx.x*256 + threadIdx.x;   // 80*256
  float f = W[i];
  _Float16 h = (_Float16)f;
  Wh[i] = h;
  Wl[i] = (_Float16)(f - (float)h);
}

// ------- enc prep: Eh = fp16(enc) [b][s][d];  EVt = fp16(enc+emb) transposed [b][d][s] ---
__global__ __launch_bounds__(256) void k_eprep(const float* __restrict__ enc,
    const float* __restrict__ emb, _Float16* __restrict__ Eh,
    _Float16* __restrict__ EVt)
{
  __shared__ float ls[64][65];
  int blk = blockIdx.x;                  // 32 b * 16 st * 4 dt = 2048
  int dt = blk & 3, st = (blk>>2) & 15, b = blk >> 6;
  int s0 = st*64, d0 = dt*64;
  int tid = threadIdx.x;
  for (int k=0;k<16;k++){
    int idx = k*256 + tid;
    int r = idx >> 6, c = idx & 63;
    size_t gi = ((size_t)b*TE + s0 + r)*DIM + d0 + c;
    float e = enc[gi];
    ls[r][c] = e + emb[gi];
    Eh[gi] = (_Float16)e;
  }
  __syncthreads();
  for (int k=0;k<16;k++){
    int idx = k*256 + tid;
    int r = idx >> 6, c = idx & 63;
    EVt[((size_t)b*DIM + d0 + r)*TE + s0 + c] = (_Float16)ls[c][r];
  }
}

// ---------- input linear + shift-right as fp16 MFMA: X = shift(mel) @ W_lin^T ----------
__global__ __launch_bounds__(256) void k_lin_mfma(const float* __restrict__ mel,
    const _Float16* __restrict__ Wh, const _Float16* __restrict__ Wl,
    const float* __restrict__ bias, _Float16* __restrict__ X)
{
  __shared__ __align__(16) _Float16 ms[64*104];   // 64 rows x 96 cols (pad 104)
  int blk = blockIdx.x;                 // 1024: 32 b x 32 t-tiles
  int b = blk >> 5;
  int t0 = (blk & 31) << 6;
  int tid = threadIdx.x;

  for (int i = tid; i < 64*12; i += 256){
    int row = i / 12, cg = (i - row*12) * 8;
    int t = t0 + row - 1;               // shifted: X[t] = lin(mel[t-1])
    f16x8 v = {};
    if (t >= 0 && cg < INDIM){
      const float4* p = (const float4*)(mel + ((size_t)b*TD + t)*INDIM + cg);
      float4 f0 = p[0], f1 = p[1];
      v[0]=(_Float16)f0.x; v[1]=(_Float16)f0.y; v[2]=(_Float16)f0.z; v[3]=(_Float16)f0.w;
      v[4]=(_Float16)f1.x; v[5]=(_Float16)f1.y; v[6]=(_Float16)f1.z; v[7]=(_Float16)f1.w;
    }
    *(f16x8*)&ms[row*104 + cg] = v;
  }
  __syncthreads();

  int wave = tid >> 6, lane = tid & 63;
  int l15 = lane & 15, l4 = lane >> 4;
  int mb = wave << 4;

  f16x8 am[3];
  #pragma unroll
  for (int kc=0;kc<3;kc++) am[kc] = *(f16x8*)&ms[(mb + l15)*104 + kc*32 + l4*8];

  for (int dt=0; dt<16; dt++){
    size_t wrow = (size_t)(dt*16 + l15)*96 + l4*8;
    f32x4 a = (f32x4){0.f,0.f,0.f,0.f};
    #pragma unroll
    for (int kc=0;kc<3;kc++){
      f16x8 bh = *(const f16x8*)(Wh + wrow + kc*32);
      f16x8 bl = *(const f16x8*)(Wl + wrow + kc*32);
      a = __builtin_amdgcn_mfma_f32_16x16x32_f16(am[kc], bh, a, 0,0,0);
      a = __builtin_amdgcn_mfma_f32_16x16x32_f16(am[kc], bl, a, 0,0,0);
    }
    int d = dt*16 + l15;
    float bv = bias[d];
    #pragma unroll
    for (int r=0;r<4;r++){
      int m = mb + l4*4 + r;
      int t = t0 + m;
      X[((size_t)b*TD + t)*DIM + d] = (t==0) ? (_Float16)0.f : (_Float16)(a[r] + bv);
    }
  }
}

// ---------------- conv-GLU as fp16 MFMA GEMM ----------------
template<int TIN_F32, int TOUT_F32>
__global__ __launch_bounds__(256) void k_conv_mfma(const void* __restrict__ Xin_,
    const _Float16* __restrict__ Wf, const float* __restrict__ bias,
    void* __restrict__ Hout_)
{
  __shared__ __align__(16) _Float16 as[68*264];   // 35.9 KB
  int id = blockIdx.x;
  int dtile = id & 3, mtile = id >> 2;
  int b = mtile >> 5;
  int t0 = (mtile & 31) << 6;
  int d0 = dtile << 6;
  int tid = threadIdx.x;

  for (int i = tid; i < 68*32; i += 256){
    int row = i >> 5, cg = (i & 31) << 3;
    int t = t0 - 4 + row;
    f16x8 v = {};
    if (t >= 0){
      if (TIN_F32){
        const float4* p = (const float4*)((const float*)Xin_ + ((size_t)b*TD + t)*DIM + cg);
        float4 f0 = p[0], f1 = p[1];
        v[0]=(_Float16)f0.x; v[1]=(_Float16)f0.y; v[2]=(_Float16)f0.z; v[3]=(_Float16)f0.w;
        v[4]=(_Float16)f1.x; v[5]=(_Float16)f1.y; v[6]=(_Float16)f1.z; v[7]=(_Float16)f1.w;
      } else {
        v = *(const f16x8*)((const _Float16*)Xin_ + ((size_t)b*TD + t)*DIM + cg);
      }
    }
    *(f16x8*)&as[row*264 + cg] = v;
  }
  __syncthreads();

  int lane = tid & 63, wave = tid >> 6;
  int l15 = lane & 15, l4 = lane >> 4;
  int dA = d0 + (wave << 4) + l15;

  const _Float16* pA = Wf + (size_t)dA*1280 + l4*8;
  const _Float16* pG = Wf + (size_t)(256 + dA)*1280 + l4*8;

  f32x4 aca[4], acg[4];
  #pragma unroll
  for (int mt=0;mt<4;mt++){ aca[mt]=(f32x4){0.f,0.f,0.f,0.f}; acg[mt]=(f32x4){0.f,0.f,0.f,0.f}; }

  f16x8 bA = *(const f16x8*)pA;
  f16x8 bG = *(const f16x8*)pG;
  #pragma unroll
  for (int kc = 0; kc < 40; ++kc){
    f16x8 nA = bA, nG = bG;
    if (kc < 39){
      nA = *(const f16x8*)(pA + (kc+1)*32);
      nG = *(const f16x8*)(pG + (kc+1)*32);
    }
    int tap = kc >> 3;
    int ic0 = (kc & 7) << 5;
    int abase = (l15 + tap)*264 + ic0 + l4*8;
    #pragma unroll
    for (int mt=0;mt<4;mt++){
      f16x8 av = *(f16x8*)&as[abase + mt*16*264];
      aca[mt] = __builtin_amdgcn_mfma_f32_16x16x32_f16(av, bA, aca[mt], 0,0,0);
      acg[mt] = __builtin_amdgcn_mfma_f32_16x16x32_f16(av, bG, acg[mt], 0,0,0);
    }
    bA = nA; bG = nG;
  }

  const float is2 = 0.7071067811865476f;
  float ba = bias[dA], bg = bias[256 + dA];
  #pragma unroll
  for (int mt=0; mt<4; mt++){
    #pragma unroll
    for (int r=0;r<4;r++){
      int m = mt*16 + l4*4 + r;
      size_t orow = ((size_t)b*TD + t0 + m)*DIM;
      float xr = TIN_F32 ? ((const float*)Xin_)[orow + dA]
                         : (float)as[(m+4)*264 + dA];
      float a = aca[mt][r] + ba;
      float g = acg[mt][r] + bg;
      float o = (a*sigmoidf_(g) + xr)*is2;
      if (TOUT_F32) ((float*)Hout_)[orow + dA] = o;
      else          ((_Float16*)Hout_)[orow + dA] = (_Float16)o;
    }
  }
}

// ---------- fused q-linear + flash attention + residual; fp16 MFMA, LDS-staged K/V ------
__global__ __launch_bounds__(256) void k_attn(float* __restrict__ H,
    const _Float16* __restrict__ Wqh, const _Float16* __restrict__ Wql,
    const float* __restrict__ bq,
    const _Float16* __restrict__ Eh, const _Float16* __restrict__ EVt)
{
  __shared__ __align__(16) _Float16 ech[64*264];        // E chunk / Q transit (33.8 KB)
  __shared__ __align__(16) _Float16 evch[256*72];       // V chunk (36.9 KB)
  __shared__ __align__(16) _Float16 pbuf[4][16][72];    // 9.2 KB

  int i = blockIdx.x;                   // XCD swizzle: same-batch blocks share an XCD
  int b = (i & 7) | ((i >> 8) << 3);
  int t0 = ((i >> 3) & 31) << 6;
  int tid = threadIdx.x;
  int wave = tid >> 6, lane = tid & 63;
  int l15 = lane & 15, l4 = lane >> 4;
  int mb = wave << 4;

  f16x8 ah[8];
  {
    const float* hrow = H + ((size_t)b*TD + t0 + mb + l15)*DIM;
    #pragma unroll
    for (int kc=0;kc<8;kc++){
      const float4* p = (const float4*)(hrow + kc*32 + l4*8);
      float4 f0 = p[0], f1 = p[1];
      f16x8 v;
      v[0]=(_Float16)f0.x; v[1]=(_Float16)f0.y; v[2]=(_Float16)f0.z; v[3]=(_Float16)f0.w;
      v[4]=(_Float16)f1.x; v[5]=(_Float16)f1.y; v[6]=(_Float16)f1.z; v[7]=(_Float16)f1.w;
      ah[kc] = v;
    }
  }

  f32x4 qacc[16];
  for (int ot=0;ot<16;ot++){
    size_t wrow = (size_t)(ot*16 + l15)*256 + l4*8;
    f32x4 a = (f32x4){0.f,0.f,0.f,0.f};
    #pragma unroll
    for (int kc=0;kc<8;kc++){
      f16x8 bh = *(const f16x8*)(Wqh + wrow + kc*32);
      f16x8 bl = *(const f16x8*)(Wql + wrow + kc*32);
      a = __builtin_amdgcn_mfma_f32_16x16x32_f16(ah[kc], bh, a, 0,0,0);
      a = __builtin_amdgcn_mfma_f32_16x16x32_f16(ah[kc], bl, a, 0,0,0);
    }
    qacc[ot] = a;
  }
  #pragma unroll
  for (int ot=0;ot<16;ot++){
    float bqv = bq[ot*16 + l15];
    #pragma unroll
    for (int r=0;r<4;r++) qacc[ot][r] += bqv;
  }

  #pragma unroll
  for (int ot=0;ot<16;ot++){
    int o = ot*16 + l15;
    #pragma unroll
    for (int r=0;r<4;r++)
      ech[(mb + l4*4 + r)*264 + o] = (_Float16)qacc[ot][r];
  }
  f16x8 aqh[8];
  #pragma unroll
  for (int kc=0;kc<8;kc++) aqh[kc] = *(f16x8*)&ech[(mb + l15)*264 + kc*32 + l4*8];
  #pragma unroll
  for (int ot=0;ot<16;ot++){
    int o = ot*16 + l15;
    #pragma unroll
    for (int r=0;r<4;r++){
      float v = qacc[ot][r];
      _Float16 h = (_Float16)v;
      ech[(mb + l4*4 + r)*264 + o] = (_Float16)(v - (float)h);
    }
  }
  f16x8 aql[8];
  #pragma unroll
  for (int kc=0;kc<8;kc++) aql[kc] = *(f16x8*)&ech[(mb + l15)*264 + kc*32 + l4*8];

  f32x4 oacc[16];
  #pragma unroll
  for (int dt=0;dt<16;dt++) oacc[dt] = (f32x4){0.f,0.f,0.f,0.f};
  float mrun[4], lrun[4];
  #pragma unroll
  for (int r=0;r<4;r++){ mrun[r] = -3.0e38f; lrun[r] = 0.f; }

  const _Float16* Ehb = Eh + (size_t)b*TE*DIM;
  const _Float16* EVb = EVt + (size_t)b*DIM*TE;

  for (int s0 = 0; s0 < TE; s0 += 64){
    __syncthreads();
    #pragma unroll
    for (int it=0; it<8; it++){
      int slot = it*256 + tid;
      int row = slot >> 5, cg = (slot & 31) << 3;
      *(f16x8*)&ech[row*264 + cg] = *(const f16x8*)(Ehb + (size_t)(s0+row)*DIM + cg);
    }
    #pragma unroll
    for (int it=0; it<8; it++){
      int slot = it*256 + tid;
      int row = slot >> 3, cg = (slot & 7) << 3;
      *(f16x8*)&evch[row*72 + cg] = *(const f16x8*)(EVb + (size_t)row*TE + s0 + cg);
    }
    __syncthreads();

    f32x4 sacc[4];
    #pragma unroll
    for (int st=0;st<4;st++){
      int er = (st*16 + l15)*264 + l4*8;
      f32x4 a = (f32x4){0.f,0.f,0.f,0.f};
      #pragma unroll
      for (int kc=0;kc<8;kc++){
        f16x8 bh = *(f16x8*)&ech[er + kc*32];
        a = __builtin_amdgcn_mfma_f32_16x16x32_f16(aqh[kc], bh, a, 0,0,0);
        a = __builtin_amdgcn_mfma_f32_16x16x32_f16(aql[kc], bh, a, 0,0,0);
      }
      sacc[st] = a;
    }
    float alpha[4];
    #pragma unroll
    for (int r=0;r<4;r++){
      float cm = fmaxf(fmaxf(sacc[0][r], sacc[1][r]), fmaxf(sacc[2][r], sacc[3][r]));
      cm = fmaxf(cm, __shfl_xor(cm, 1));
      cm = fmaxf(cm, __shfl_xor(cm, 2));
      cm = fmaxf(cm, __shfl_xor(cm, 4));
      cm = fmaxf(cm, __shfl_xor(cm, 8));
      float mnew = fmaxf(mrun[r], cm);
      alpha[r] = __expf(mrun[r] - mnew);
      mrun[r] = mnew;
      float ps = 0.f;
      #pragma unroll
      for (int st=0;st<4;st++){
        float p = __expf(sacc[st][r] - mnew);
        sacc[st][r] = p;
        ps += p;
      }
      ps += __shfl_xor(ps, 1);
      ps += __shfl_xor(ps, 2);
      ps += __shfl_xor(ps, 4);
      ps += __shfl_xor(ps, 8);
      lrun[r] = lrun[r]*alpha[r] + ps;
    }
    #pragma unroll
    for (int dt=0;dt<16;dt++){
      #pragma unroll
      for (int r=0;r<4;r++) oacc[dt][r] *= alpha[r];
    }
    #pragma unroll
    for (int st=0;st<4;st++){
      #pragma unroll
      for (int r=0;r<4;r++)
        pbuf[wave][l4*4+r][st*16+l15] = (_Float16)sacc[st][r];
    }
    #pragma unroll
    for (int kp=0;kp<2;kp++){
      f16x8 ap = *(f16x8*)&pbuf[wave][l15][kp*32 + l4*8];
      #pragma unroll
      for (int dt=0;dt<16;dt++){
        f16x8 bv = *(f16x8*)&evch[(dt*16 + l15)*72 + kp*32 + l4*8];
        oacc[dt] = __builtin_amdgcn_mfma_f32_16x16x32_f16(ap, bv, oacc[dt], 0,0,0);
      }
    }
  }

  float linv[4];
  #pragma unroll
  for (int r=0;r<4;r++) linv[r] = 1.f / lrun[r];
  #pragma unroll
  for (int dt=0;dt<16;dt++){
    int d = dt*16 + l15;
    #pragma unroll
    for (int r=0;r<4;r++){
      int t = t0 + mb + l4*4 + r;
      float* hp = &H[((size_t)b*TD + t)*DIM + d];
      *hp += oacc[dt][r] * linv[r];
    }
  }
}

// ---------- output projection as fp16 MFMA: out = Pb @ (Wph+Wpl)^T + bias ----------
__global__ __launch_bounds__(256) void k_proj_mfma(const _Float16* __restrict__ Hin,
    const _Float16* __restrict__ Wh, const _Float16* __restrict__ Wl,
    const float* __restrict__ bias, float* __restrict__ out)
{
  int blk = blockIdx.x;                 // 1024: 32 b x 32 t-tiles
  int b = blk >> 5;
  int t0 = (blk & 31) << 6;
  int tid = threadIdx.x;
  int wave = tid >> 6, lane = tid & 63;
  int l15 = lane & 15, l4 = lane >> 4;
  int mb = wave << 4;

  f16x8 ah[8];
  const _Float16* hrow = Hin + ((size_t)b*TD + t0 + mb + l15)*DIM;
  #pragma unroll
  for (int kc=0;kc<8;kc++) ah[kc] = *(const f16x8*)(hrow + kc*32 + l4*8);

  #pragma unroll
  for (int nt=0; nt<5; nt++){
    size_t wrow = (size_t)(nt*16 + l15)*256 + l4*8;
    f32x4 a = (f32x4){0.f,0.f,0.f,0.f};
    #pragma unroll
    for (int kc=0;kc<8;kc++){
      f16x8 bh = *(const f16x8*)(Wh + wrow + kc*32);
      f16x8 bl = *(const f16x8*)(Wl + wrow + kc*32);
      a = __builtin_amdgcn_mfma_f32_16x16x32_f16(ah[kc], bh, a, 0,0,0);
      a = __builtin_amdgcn_mfma_f32_16x16x32_f16(ah[kc], bl, a, 0,0,0);
    }
    int n = nt*16 + l15;
    float bv = bias[n];
    #pragma unroll
    for (int r=0;r<4;r++){
      int t = t0 + mb + l4*4 + r;
      out[((size_t)b*TD + t)*INDIM + n] = a[r] + bv;
    }
  }
}

extern "C" void kernel_launch(void* const* d_in, const int* in_sizes, int n_in,
                              void* d_out, int out_size, void* d_ws, size_t ws_size,
                              hipStream_t stream) {
  const float* enc   = (const float*)d_in[0];
  const float* emb   = (const float*)d_in[1];
  const float* mel   = (const float*)d_in[2];
  const float* W_lin = (const float*)d_in[3];
  const float* b_lin = (const float*)d_in[4];
  const float* w0    = (const float*)d_in[5];
  const float* b0    = (const float*)d_in[6];
  const float* w1    = (const float*)d_in[7];
  const float* b1    = (const float*)d_in[8];
  const float* Wq    = (const float*)d_in[9];
  const float* bq    = (const float*)d_in[10];
  const float* Wp    = (const float*)d_in[11];
  const float* bp    = (const float*)d_in[12];
  float* out = (float*)d_out;

  const size_t NTOK = (size_t)BB*TD*DIM;           // 16.78M
  const size_t NE   = (size_t)BB*TE*DIM;           // 8.39M
  _Float16* Xb  = (_Float16*)d_ws;
  float*    H   = (float*)(Xb + NTOK);
  _Float16* Wf0 = (_Float16*)(H + NTOK);
  _Float16* Wf1 = Wf0 + (size_t)512*1280;
  _Float16* Wqh = Wf1 + (size_t)512*1280;
  _Float16* Wql = Wqh + 65536;
  _Float16* Wlh = Wql + 65536;                     // 256*96
  _Float16* Wll = Wlh + 24576;
  _Float16* Wph = Wll + 24576;                     // 80*256
  _Float16* Wpl = Wph + 20480;
  _Float16* Eh  = Xb;                              // after conv0 consumes Xb
  _Float16* EVt = Xb + NE;
  _Float16* Pb  = Xb;                              // after attn consumes Eh/EVt

  k_wprep    <<<2560, 256, 0, stream>>>(w0, Wf0);
  k_wprep    <<<2560, 256, 0, stream>>>(w1, Wf1);
  k_qwprep   <<<256,  256, 0, stream>>>(Wq, Wqh, Wql);
  k_lwprep   <<<96,   256, 0, stream>>>(W_lin, Wlh, Wll);
  k_pwprep   <<<80,   256, 0, stream>>>(Wp, Wph, Wpl);
  k_lin_mfma <<<1024, 256, 0, stream>>>(mel, Wlh, Wll, b_lin, Xb);
  k_conv_mfma<0,1><<<4096, 256, 0, stream>>>(Xb, Wf0, b0, H);
  k_eprep    <<<2048, 256, 0, stream>>>(enc, emb, Eh, EVt);
  k_attn     <<<1024, 256, 0, stream>>>(H, Wqh, Wql, bq, Eh, EVt);
  k_conv_mfma<1,0><<<4096, 256, 0, stream>>>(H, Wf1, b1, Pb);
  k_proj_mfma<<<1024, 256, 0, stream>>>(Pb, Wph, Wpl, bp, out);
}